// Round 1
// baseline (869.554 us; speedup 1.0000x reference)
//
#include <hip/hip_runtime.h>
#include <math.h>

#define B_    2
#define NSEQ  8192
#define DIM_  512
#define H_    8
#define DH_   64
#define F_    256
#define M_    (B_*NSEQ)      // 16384
#define QKV_  1536

// ---------------------------------------------------------------------------
// K1/K5: generic NT GEMM  C[M][N] = A[M][K] * B[N][K]^T (+bias[N])
// tile 128x128, Ktile 16, 256 threads, 8x8 microtile (2x2 blocks of 4x4).
// LDS stride 132 (pad +4): transpose-write 2-way conflict (free), b128 reads ok.
// ---------------------------------------------------------------------------
__global__ __launch_bounds__(256) void gemm_nt(const float* __restrict__ A,
                                               const float* __restrict__ Bm,
                                               const float* __restrict__ bias,
                                               float* __restrict__ C,
                                               int M, int N, int K) {
    __shared__ float As[16][132];
    __shared__ float Bs[16][132];
    const int t  = threadIdx.x;
    const int tx = t & 15, ty = t >> 4;
    const int m0 = blockIdx.y * 128, n0 = blockIdx.x * 128;

    float acc[8][8];
#pragma unroll
    for (int i = 0; i < 8; i++)
#pragma unroll
        for (int j = 0; j < 8; j++) acc[i][j] = 0.f;

    for (int k0 = 0; k0 < K; k0 += 16) {
#pragma unroll
        for (int i = 0; i < 2; i++) {
            int flat = t + i * 256;          // 0..511
            int row  = flat >> 2;            // 0..127
            int kq   = (flat & 3) * 4;       // 0,4,8,12
            float4 a4 = *(const float4*)(A + (size_t)(m0 + row) * K + k0 + kq);
            As[kq + 0][row] = a4.x; As[kq + 1][row] = a4.y;
            As[kq + 2][row] = a4.z; As[kq + 3][row] = a4.w;
            float4 b4 = *(const float4*)(Bm + (size_t)(n0 + row) * K + k0 + kq);
            Bs[kq + 0][row] = b4.x; Bs[kq + 1][row] = b4.y;
            Bs[kq + 2][row] = b4.z; Bs[kq + 3][row] = b4.w;
        }
        __syncthreads();
#pragma unroll
        for (int kk = 0; kk < 16; kk++) {
            float4 alo = *(const float4*)&As[kk][ty * 4];
            float4 ahi = *(const float4*)&As[kk][64 + ty * 4];
            float4 blo = *(const float4*)&Bs[kk][tx * 4];
            float4 bhi = *(const float4*)&Bs[kk][64 + tx * 4];
            float a8[8] = {alo.x, alo.y, alo.z, alo.w, ahi.x, ahi.y, ahi.z, ahi.w};
            float b8[8] = {blo.x, blo.y, blo.z, blo.w, bhi.x, bhi.y, bhi.z, bhi.w};
#pragma unroll
            for (int i = 0; i < 8; i++)
#pragma unroll
                for (int j = 0; j < 8; j++) acc[i][j] = fmaf(a8[i], b8[j], acc[i][j]);
        }
        __syncthreads();
    }
#pragma unroll
    for (int i = 0; i < 8; i++) {
        int row = m0 + ((i < 4) ? (ty * 4 + i) : (64 + ty * 4 + (i - 4)));
#pragma unroll
        for (int jh = 0; jh < 2; jh++) {
            int col = n0 + jh * 64 + tx * 4;
            float4 o;
            o.x = acc[i][jh * 4 + 0]; o.y = acc[i][jh * 4 + 1];
            o.z = acc[i][jh * 4 + 2]; o.w = acc[i][jh * 4 + 3];
            if (bias) {
                o.x += bias[col]; o.y += bias[col + 1];
                o.z += bias[col + 2]; o.w += bias[col + 3];
            }
            *(float4*)(C + (size_t)row * N + col) = o;
        }
    }
}

// ---------------------------------------------------------------------------
// K2: fused k' feature map + split-K context/ksum partials.
// grid (4 ftiles, 8 kchunks, 16 bh), 256 threads.
// Per 64-row n-chunk: load K/V tile, compute kp=exp(K·P^T) in-register (NT
// micro-GEMM), round-trip through LDS, outer-product accumulate ctx[f][dh]
// and ksum[f]. Partials written once per block (no init needed).
// ---------------------------------------------------------------------------
__global__ __launch_bounds__(256) void ctx_fused(const float* __restrict__ qkv,
                                                 const float* __restrict__ proj,
                                                 float* __restrict__ pctx,   // [8][16][256][64]
                                                 float* __restrict__ pksum)  // [8][16][256]
{
    __shared__ float Ps[64][68];
    __shared__ float Ks[64][68];
    __shared__ float Vs[64][68];
    __shared__ float KPs[64][68];
    const int t  = threadIdx.x;
    const int tx = t & 15, ty = t >> 4;
    const int f0 = blockIdx.x * 64;
    const int kc = blockIdx.y;
    const int bh = blockIdx.z;
    const int b  = bh >> 3, h = bh & 7;

#pragma unroll
    for (int i = 0; i < 4; i++) {
        int flat = t + i * 256;         // 0..1023
        int r  = flat >> 4;             // 0..63
        int d4 = (flat & 15) * 4;
        *(float4*)&Ps[r][d4] = *(const float4*)(proj + (size_t)(f0 + r) * 64 + d4);
    }

    float acc[4][4];
#pragma unroll
    for (int i = 0; i < 4; i++)
#pragma unroll
        for (int j = 0; j < 4; j++) acc[i][j] = 0.f;
    float ksacc[4] = {0.f, 0.f, 0.f, 0.f};

    const int kbase = 512 + h * 64;
    const int vbase = 1024 + h * 64;

    for (int c = 0; c < 16; c++) {
        int n0 = kc * 1024 + c * 64;
        __syncthreads();                // protect KPs/Vs reads of prev iter (+Ps first iter)
#pragma unroll
        for (int i = 0; i < 4; i++) {
            int flat = t + i * 256;
            int r  = flat >> 4;
            int d4 = (flat & 15) * 4;
            size_t rowoff = ((size_t)b * NSEQ + n0 + r) * QKV_;
            *(float4*)&Ks[r][d4] = *(const float4*)(qkv + rowoff + kbase + d4);
            *(float4*)&Vs[r][d4] = *(const float4*)(qkv + rowoff + vbase + d4);
        }
        __syncthreads();
        // kp[n][f] = exp(K[n]·P[f]);  n = ty*4+i, f = tx*4+j
        float aq[4][4];
#pragma unroll
        for (int i = 0; i < 4; i++)
#pragma unroll
            for (int j = 0; j < 4; j++) aq[i][j] = 0.f;
#pragma unroll 4
        for (int d4 = 0; d4 < 64; d4 += 4) {
            float4 ka[4], pb[4];
#pragma unroll
            for (int i = 0; i < 4; i++) ka[i] = *(const float4*)&Ks[ty * 4 + i][d4];
#pragma unroll
            for (int j = 0; j < 4; j++) pb[j] = *(const float4*)&Ps[tx * 4 + j][d4];
#pragma unroll
            for (int i = 0; i < 4; i++)
#pragma unroll
                for (int j = 0; j < 4; j++)
                    aq[i][j] += ka[i].x * pb[j].x + ka[i].y * pb[j].y +
                                ka[i].z * pb[j].z + ka[i].w * pb[j].w;
        }
#pragma unroll
        for (int i = 0; i < 4; i++)
#pragma unroll
            for (int j = 0; j < 4; j++)
                KPs[ty * 4 + i][tx * 4 + j] = __expf(aq[i][j]);
        __syncthreads();
        // ctx[f][dh] += kp[n][f]*v[n][dh];  f = ty*4+i, dh = tx*4+j
#pragma unroll 8
        for (int n = 0; n < 64; n++) {
            float4 af = *(const float4*)&KPs[n][ty * 4];
            float4 bv = *(const float4*)&Vs[n][tx * 4];
            float a4[4] = {af.x, af.y, af.z, af.w};
            float b4[4] = {bv.x, bv.y, bv.z, bv.w};
#pragma unroll
            for (int i = 0; i < 4; i++)
#pragma unroll
                for (int j = 0; j < 4; j++) acc[i][j] = fmaf(a4[i], b4[j], acc[i][j]);
            if (tx == 0) {
#pragma unroll
                for (int i = 0; i < 4; i++) ksacc[i] += a4[i];
            }
        }
    }
    const int kcbh = kc * 16 + bh;
#pragma unroll
    for (int i = 0; i < 4; i++) {
        int f = f0 + ty * 4 + i;
        float4 o = {acc[i][0], acc[i][1], acc[i][2], acc[i][3]};
        *(float4*)(pctx + ((size_t)kcbh * 256 + f) * 64 + tx * 4) = o;
    }
    if (tx == 0) {
#pragma unroll
        for (int i = 0; i < 4; i++) pksum[(size_t)kcbh * 256 + f0 + ty * 4 + i] = ksacc[i];
    }
}

// ---------------------------------------------------------------------------
// K3: reduce split-K partials.
// ---------------------------------------------------------------------------
__global__ __launch_bounds__(256) void reduce_parts(const float* __restrict__ pctx,
                                                    const float* __restrict__ pksum,
                                                    float* __restrict__ ctx,
                                                    float* __restrict__ ksum) {
    int idx = blockIdx.x * 256 + threadIdx.x;
    const int NC = 16 * 256 * 64;
    if (idx < NC) {
        float s = 0.f;
#pragma unroll
        for (int kc = 0; kc < 8; kc++) s += pctx[(size_t)kc * NC + idx];
        ctx[idx] = s;
    } else {
        int i2 = idx - NC;
        if (i2 < 16 * 256) {
            float s = 0.f;
#pragma unroll
            for (int kc = 0; kc < 8; kc++) s += pksum[kc * 16 * 256 + i2];
            ksum[i2] = s;
        }
    }
}

// ---------------------------------------------------------------------------
// K4: fused q' feature map + (q'·ctx)*D_inv.  grid (128 ntiles, 16 bh).
// Per f-chunk of 64: compute qp^T[f][n]=exp(P[f]·Qs[n]) (Q pre-scaled),
// then out[m][dh] += qp^T[f][m]*ctx[f][dh], D[m] += qp^T[f][m]*ksum[f].
// ---------------------------------------------------------------------------
__global__ __launch_bounds__(256) void attn_fused(const float* __restrict__ qkv,
                                                  const float* __restrict__ proj,
                                                  const float* __restrict__ ctx,   // [16][256][64]
                                                  const float* __restrict__ ksum,  // [16][256]
                                                  float* __restrict__ attn)        // [16384][512]
{
    __shared__ float Qs[64][68];
    __shared__ float Ps[64][68];
    __shared__ float QPT[64][68];   // [f][n]
    __shared__ float Cs[64][68];
    __shared__ float ksl[64];
    __shared__ float Dm[64];
    const int t  = threadIdx.x;
    const int tx = t & 15, ty = t >> 4;
    const int m0 = blockIdx.x * 64;
    const int bh = blockIdx.y;
    const int b  = bh >> 3, h = bh & 7;

#pragma unroll
    for (int i = 0; i < 4; i++) {
        int flat = t + i * 256;
        int r  = flat >> 4;
        int d4 = (flat & 15) * 4;
        float4 q4 = *(const float4*)(qkv + ((size_t)b * NSEQ + m0 + r) * QKV_ + h * 64 + d4);
        q4.x *= 0.125f; q4.y *= 0.125f; q4.z *= 0.125f; q4.w *= 0.125f;  // dh^-0.5
        *(float4*)&Qs[r][d4] = q4;
    }

    float acc[4][4];
#pragma unroll
    for (int i = 0; i < 4; i++)
#pragma unroll
        for (int j = 0; j < 4; j++) acc[i][j] = 0.f;
    float dacc[4] = {0.f, 0.f, 0.f, 0.f};

    for (int fc = 0; fc < 4; fc++) {
        int f0 = fc * 64;
        __syncthreads();               // protect QPT/Cs reads of prev iter (+Qs first iter)
#pragma unroll
        for (int i = 0; i < 4; i++) {
            int flat = t + i * 256;
            int r  = flat >> 4;
            int d4 = (flat & 15) * 4;
            *(float4*)&Ps[r][d4] = *(const float4*)(proj + (size_t)(f0 + r) * 64 + d4);
            *(float4*)&Cs[r][d4] = *(const float4*)(ctx + ((size_t)bh * 256 + f0 + r) * 64 + d4);
        }
        if (t < 64) ksl[t] = ksum[(size_t)bh * 256 + f0 + t];
        __syncthreads();
        // qp^T[f][n]: f = ty*4+i (from Ps), n = tx*4+j (from Qs)
        float aq[4][4];
#pragma unroll
        for (int i = 0; i < 4; i++)
#pragma unroll
            for (int j = 0; j < 4; j++) aq[i][j] = 0.f;
#pragma unroll 4
        for (int d4 = 0; d4 < 64; d4 += 4) {
            float4 pa[4], qb[4];
#pragma unroll
            for (int i = 0; i < 4; i++) pa[i] = *(const float4*)&Ps[ty * 4 + i][d4];
#pragma unroll
            for (int j = 0; j < 4; j++) qb[j] = *(const float4*)&Qs[tx * 4 + j][d4];
#pragma unroll
            for (int i = 0; i < 4; i++)
#pragma unroll
                for (int j = 0; j < 4; j++)
                    aq[i][j] += pa[i].x * qb[j].x + pa[i].y * qb[j].y +
                                pa[i].z * qb[j].z + pa[i].w * qb[j].w;
        }
#pragma unroll
        for (int i = 0; i < 4; i++)
#pragma unroll
            for (int j = 0; j < 4; j++)
                QPT[ty * 4 + i][tx * 4 + j] = __expf(aq[i][j]);
        __syncthreads();
        // out[m][dh] += qp[m][f]*ctx[f][dh];  m = ty*4+i, dh = tx*4+j
#pragma unroll 8
        for (int f = 0; f < 64; f++) {
            float4 am = *(const float4*)&QPT[f][ty * 4];
            float4 bc = *(const float4*)&Cs[f][tx * 4];
            float a4[4] = {am.x, am.y, am.z, am.w};
            float b4[4] = {bc.x, bc.y, bc.z, bc.w};
#pragma unroll
            for (int i = 0; i < 4; i++)
#pragma unroll
                for (int j = 0; j < 4; j++) acc[i][j] = fmaf(a4[i], b4[j], acc[i][j]);
            if (tx == 0) {
                float kv = ksl[f];
#pragma unroll
                for (int i = 0; i < 4; i++) dacc[i] = fmaf(a4[i], kv, dacc[i]);
            }
        }
    }
    if (tx == 0) {
#pragma unroll
        for (int i = 0; i < 4; i++) Dm[ty * 4 + i] = dacc[i];
    }
    __syncthreads();
#pragma unroll
    for (int i = 0; i < 4; i++) {
        float rinv = 1.f / (Dm[ty * 4 + i] + 1e-6f);
        float4 o = {acc[i][0] * rinv, acc[i][1] * rinv, acc[i][2] * rinv, acc[i][3] * rinv};
        *(float4*)(attn + ((size_t)b * NSEQ + m0 + ty * 4 + i) * 512 + h * 64 + tx * 4) = o;
    }
}

// ---------------------------------------------------------------------------
extern "C" void kernel_launch(void* const* d_in, const int* in_sizes, int n_in,
                              void* d_out, int out_size, void* d_ws, size_t ws_size,
                              hipStream_t stream) {
    const float* x    = (const float*)d_in[0];
    const float* Wqkv = (const float*)d_in[1];
    const float* Wout = (const float*)d_in[2];
    const float* bout = (const float*)d_in[3];
    const float* proj = (const float*)d_in[4];

    float* ws    = (float*)d_ws;
    float* qkv   = ws;                                   // 16384*1536 = 25165824
    float* pctx  = qkv + (size_t)M_ * QKV_;              // 8*16*256*64 = 2097152
    float* pksum = pctx + (size_t)8 * 16 * 256 * 64;     // 8*16*256 = 32768
    float* ctx   = pksum + (size_t)8 * 16 * 256;         // 16*256*64 = 262144
    float* ksum  = ctx + (size_t)16 * 256 * 64;          // 16*256 = 4096
    float* attn  = ksum + (size_t)16 * 256;              // 16384*512 = 8388608
    float* outp  = (float*)d_out;                        // total ws: ~143.8 MB

    // 1) qkv = x @ Wqkv^T                    [16384 x 1536], K=512
    gemm_nt<<<dim3(QKV_ / 128, M_ / 128), 256, 0, stream>>>(x, Wqkv, nullptr, qkv, M_, QKV_, DIM_);
    // 2) context/ksum partials (k' fused)
    ctx_fused<<<dim3(4, 8, 16), 256, 0, stream>>>(qkv, proj, pctx, pksum);
    // 3) reduce partials
    reduce_parts<<<dim3((16 * 256 * 64 + 16 * 256 + 255) / 256), 256, 0, stream>>>(pctx, pksum, ctx, ksum);
    // 4) attn_out = (q' @ ctx) * D_inv (q' fused)   [16384 x 512]
    attn_fused<<<dim3(128, 16), 256, 0, stream>>>(qkv, proj, ctx, ksum, attn);
    // 5) out = attn_out @ Wout^T + bout      [16384 x 512], K=512
    gemm_nt<<<dim3(512 / 128, M_ / 128), 256, 0, stream>>>(attn, Wout, bout, outp, M_, 512, 512);
}

// Round 2
// 564.640 us; speedup vs baseline: 1.5400x; 1.5400x over previous
//
#include <hip/hip_runtime.h>
#include <math.h>

#define B_    2
#define NSEQ  8192
#define DIM_  512
#define H_    8
#define DH_   64
#define F_    256
#define M_    (B_*NSEQ)      // 16384
#define QKV_  1536

typedef __attribute__((ext_vector_type(8))) short     short8;
typedef __attribute__((ext_vector_type(4))) float     float4v;
typedef __attribute__((ext_vector_type(4))) unsigned short ushort4v;
typedef __attribute__((ext_vector_type(8))) unsigned short ushort8v;

__device__ __forceinline__ unsigned short f2bf(float f) {
    unsigned u = __float_as_uint(f);
    u += 0x7FFFu + ((u >> 16) & 1u);   // RNE
    return (unsigned short)(u >> 16);
}

__device__ __forceinline__ void glds16(const void* g, void* s) {
    __builtin_amdgcn_global_load_lds(
        (const __attribute__((address_space(1))) unsigned int*)g,
        (__attribute__((address_space(3))) unsigned int*)s,
        16, 0, 0);
}

// ---------------------------------------------------------------------------
// fp32 -> bf16 elementwise convert (8 elems/thread)
// ---------------------------------------------------------------------------
__global__ __launch_bounds__(256) void cvt_bf16(const float* __restrict__ in,
                                                unsigned short* __restrict__ out,
                                                int n8) {
    int i = blockIdx.x * 256 + threadIdx.x;
    if (i >= n8) return;
    float4 a = ((const float4*)in)[2 * i];
    float4 b = ((const float4*)in)[2 * i + 1];
    ushort8v o;
    o[0] = f2bf(a.x); o[1] = f2bf(a.y); o[2] = f2bf(a.z); o[3] = f2bf(a.w);
    o[4] = f2bf(b.x); o[5] = f2bf(b.y); o[6] = f2bf(b.z); o[7] = f2bf(b.w);
    ((ushort8v*)out)[i] = o;
}

// ---------------------------------------------------------------------------
// K1/K5: NT GEMM via MFMA (m97 structure).
// C[M][N] = A[M][K](bf16) * B[N][K]^T(bf16) (+bias), fp32 accumulate/out.
// 128x128 tile, 256 thr = 4 waves (2x2), each wave 64x64 = 4x4 mfma 16x16x32.
// LDS fragment-order layout: granule(16B) index = rb8*64 + kquad*16 + row16.
// Staging: global_load_lds width 16, wave-uniform base + lane*16 (required).
// Fragment read: ds_read_b128 at base + lane*16 -> conflict-free.
// ---------------------------------------------------------------------------
__global__ __launch_bounds__(256) void gemm_nt_bf16(const unsigned short* __restrict__ A,
                                                    const unsigned short* __restrict__ Bm,
                                                    const float* __restrict__ bias,
                                                    float* __restrict__ C,
                                                    int M, int N, int K) {
    __shared__ __align__(16) unsigned short As[128 * 32];
    __shared__ __align__(16) unsigned short Bs[128 * 32];
    const int t  = threadIdx.x;
    const int w  = t >> 6, l = t & 63;
    const int wm = w >> 1, wn = w & 1;
    const int m0 = blockIdx.y * 128, n0 = blockIdx.x * 128;
    const int lrow = l & 15;          // staging: row within 16-row block
    const int lkb  = l >> 4;          // staging: k-quad (8 elems)

    float4v acc[4][4];
#pragma unroll
    for (int mi = 0; mi < 4; mi++)
#pragma unroll
        for (int ni = 0; ni < 4; ni++) acc[mi][ni] = (float4v){0.f, 0.f, 0.f, 0.f};

    for (int k0 = 0; k0 < K; k0 += 32) {
        __syncthreads();   // prior ds_reads done before LDS overwrite
#pragma unroll
        for (int i = 0; i < 2; i++) {
            int rb8 = w * 2 + i;                   // 0..7 across waves
            int row = rb8 * 16 + lrow;
            glds16(A + (size_t)(m0 + row) * K + k0 + lkb * 8, &As[rb8 * 512]);
            glds16(Bm + (size_t)(n0 + row) * K + k0 + lkb * 8, &Bs[rb8 * 512]);
        }
        __syncthreads();   // compiler emits vmcnt(0) drain before barrier

        short8 af[4], bfr[4];
#pragma unroll
        for (int mi = 0; mi < 4; mi++)
            af[mi] = *(const short8*)&As[((wm * 4 + mi) * 64 + l) * 8];
#pragma unroll
        for (int ni = 0; ni < 4; ni++)
            bfr[ni] = *(const short8*)&Bs[((wn * 4 + ni) * 64 + l) * 8];
#pragma unroll
        for (int mi = 0; mi < 4; mi++)
#pragma unroll
            for (int ni = 0; ni < 4; ni++)
                acc[mi][ni] = __builtin_amdgcn_mfma_f32_16x16x32_bf16(
                    af[mi], bfr[ni], acc[mi][ni], 0, 0, 0);
    }

    const int q = l >> 4, c = l & 15;   // C/D layout: col=lane&15, row=quad*4+reg
#pragma unroll
    for (int mi = 0; mi < 4; mi++) {
        int row0 = m0 + wm * 64 + mi * 16 + q * 4;
#pragma unroll
        for (int ni = 0; ni < 4; ni++) {
            int col = n0 + wn * 64 + ni * 16 + c;
            float bv = bias ? bias[col] : 0.f;
#pragma unroll
            for (int r = 0; r < 4; r++)
                C[(size_t)(row0 + r) * N + col] = acc[mi][ni][r] + bv;
        }
    }
}

// ---------------------------------------------------------------------------
// K2: fused k' feature map + split-K context/ksum partials (fp32 VALU).
// ---------------------------------------------------------------------------
__global__ __launch_bounds__(256) void ctx_fused(const float* __restrict__ qkv,
                                                 const float* __restrict__ proj,
                                                 float* __restrict__ pctx,   // [8][16][256][64]
                                                 float* __restrict__ pksum)  // [8][16][256]
{
    __shared__ float Ps[64][68];
    __shared__ float Ks[64][68];
    __shared__ float Vs[64][68];
    __shared__ float KPs[64][68];
    const int t  = threadIdx.x;
    const int tx = t & 15, ty = t >> 4;
    const int f0 = blockIdx.x * 64;
    const int kc = blockIdx.y;
    const int bh = blockIdx.z;
    const int b  = bh >> 3, h = bh & 7;

#pragma unroll
    for (int i = 0; i < 4; i++) {
        int flat = t + i * 256;
        int r  = flat >> 4;
        int d4 = (flat & 15) * 4;
        *(float4*)&Ps[r][d4] = *(const float4*)(proj + (size_t)(f0 + r) * 64 + d4);
    }

    float acc[4][4];
#pragma unroll
    for (int i = 0; i < 4; i++)
#pragma unroll
        for (int j = 0; j < 4; j++) acc[i][j] = 0.f;
    float ksacc[4] = {0.f, 0.f, 0.f, 0.f};

    const int kbase = 512 + h * 64;
    const int vbase = 1024 + h * 64;

    for (int c = 0; c < 16; c++) {
        int n0 = kc * 1024 + c * 64;
        __syncthreads();
#pragma unroll
        for (int i = 0; i < 4; i++) {
            int flat = t + i * 256;
            int r  = flat >> 4;
            int d4 = (flat & 15) * 4;
            size_t rowoff = ((size_t)b * NSEQ + n0 + r) * QKV_;
            *(float4*)&Ks[r][d4] = *(const float4*)(qkv + rowoff + kbase + d4);
            *(float4*)&Vs[r][d4] = *(const float4*)(qkv + rowoff + vbase + d4);
        }
        __syncthreads();
        float aq[4][4];
#pragma unroll
        for (int i = 0; i < 4; i++)
#pragma unroll
            for (int j = 0; j < 4; j++) aq[i][j] = 0.f;
#pragma unroll 4
        for (int d4 = 0; d4 < 64; d4 += 4) {
            float4 ka[4], pb[4];
#pragma unroll
            for (int i = 0; i < 4; i++) ka[i] = *(const float4*)&Ks[ty * 4 + i][d4];
#pragma unroll
            for (int j = 0; j < 4; j++) pb[j] = *(const float4*)&Ps[tx * 4 + j][d4];
#pragma unroll
            for (int i = 0; i < 4; i++)
#pragma unroll
                for (int j = 0; j < 4; j++)
                    aq[i][j] += ka[i].x * pb[j].x + ka[i].y * pb[j].y +
                                ka[i].z * pb[j].z + ka[i].w * pb[j].w;
        }
#pragma unroll
        for (int i = 0; i < 4; i++)
#pragma unroll
            for (int j = 0; j < 4; j++)
                KPs[ty * 4 + i][tx * 4 + j] = __expf(aq[i][j]);
        __syncthreads();
#pragma unroll 8
        for (int n = 0; n < 64; n++) {
            float4 af = *(const float4*)&KPs[n][ty * 4];
            float4 bv = *(const float4*)&Vs[n][tx * 4];
            float a4[4] = {af.x, af.y, af.z, af.w};
            float b4[4] = {bv.x, bv.y, bv.z, bv.w};
#pragma unroll
            for (int i = 0; i < 4; i++)
#pragma unroll
                for (int j = 0; j < 4; j++) acc[i][j] = fmaf(a4[i], b4[j], acc[i][j]);
            if (tx == 0) {
#pragma unroll
                for (int i = 0; i < 4; i++) ksacc[i] += a4[i];
            }
        }
    }
    const int kcbh = kc * 16 + bh;
#pragma unroll
    for (int i = 0; i < 4; i++) {
        int f = f0 + ty * 4 + i;
        float4 o = {acc[i][0], acc[i][1], acc[i][2], acc[i][3]};
        *(float4*)(pctx + ((size_t)kcbh * 256 + f) * 64 + tx * 4) = o;
    }
    if (tx == 0) {
#pragma unroll
        for (int i = 0; i < 4; i++) pksum[(size_t)kcbh * 256 + f0 + ty * 4 + i] = ksacc[i];
    }
}

// ---------------------------------------------------------------------------
// K3: reduce split-K partials.
// ---------------------------------------------------------------------------
__global__ __launch_bounds__(256) void reduce_parts(const float* __restrict__ pctx,
                                                    const float* __restrict__ pksum,
                                                    float* __restrict__ ctx,
                                                    float* __restrict__ ksum) {
    int idx = blockIdx.x * 256 + threadIdx.x;
    const int NC = 16 * 256 * 64;
    if (idx < NC) {
        float s = 0.f;
#pragma unroll
        for (int kc = 0; kc < 8; kc++) s += pctx[(size_t)kc * NC + idx];
        ctx[idx] = s;
    } else {
        int i2 = idx - NC;
        if (i2 < 16 * 256) {
            float s = 0.f;
#pragma unroll
            for (int kc = 0; kc < 8; kc++) s += pksum[kc * 16 * 256 + i2];
            ksum[i2] = s;
        }
    }
}

// ---------------------------------------------------------------------------
// K4: fused q' feature map + (q'.ctx)*D_inv -> bf16 output (feeds gemm2).
// ---------------------------------------------------------------------------
__global__ __launch_bounds__(256) void attn_fused(const float* __restrict__ qkv,
                                                  const float* __restrict__ proj,
                                                  const float* __restrict__ ctx,   // [16][256][64]
                                                  const float* __restrict__ ksum,  // [16][256]
                                                  unsigned short* __restrict__ attn) // bf16 [16384][512]
{
    __shared__ float Qs[64][68];
    __shared__ float Ps[64][68];
    __shared__ float QPT[64][68];   // [f][n]
    __shared__ float Cs[64][68];
    __shared__ float ksl[64];
    __shared__ float Dm[64];
    const int t  = threadIdx.x;
    const int tx = t & 15, ty = t >> 4;
    const int m0 = blockIdx.x * 64;
    const int bh = blockIdx.y;
    const int b  = bh >> 3, h = bh & 7;

#pragma unroll
    for (int i = 0; i < 4; i++) {
        int flat = t + i * 256;
        int r  = flat >> 4;
        int d4 = (flat & 15) * 4;
        float4 q4 = *(const float4*)(qkv + ((size_t)b * NSEQ + m0 + r) * QKV_ + h * 64 + d4);
        q4.x *= 0.125f; q4.y *= 0.125f; q4.z *= 0.125f; q4.w *= 0.125f;
        *(float4*)&Qs[r][d4] = q4;
    }

    float acc[4][4];
#pragma unroll
    for (int i = 0; i < 4; i++)
#pragma unroll
        for (int j = 0; j < 4; j++) acc[i][j] = 0.f;
    float dacc[4] = {0.f, 0.f, 0.f, 0.f};

    for (int fc = 0; fc < 4; fc++) {
        int f0 = fc * 64;
        __syncthreads();
#pragma unroll
        for (int i = 0; i < 4; i++) {
            int flat = t + i * 256;
            int r  = flat >> 4;
            int d4 = (flat & 15) * 4;
            *(float4*)&Ps[r][d4] = *(const float4*)(proj + (size_t)(f0 + r) * 64 + d4);
            *(float4*)&Cs[r][d4] = *(const float4*)(ctx + ((size_t)bh * 256 + f0 + r) * 64 + d4);
        }
        if (t < 64) ksl[t] = ksum[(size_t)bh * 256 + f0 + t];
        __syncthreads();
        float aq[4][4];
#pragma unroll
        for (int i = 0; i < 4; i++)
#pragma unroll
            for (int j = 0; j < 4; j++) aq[i][j] = 0.f;
#pragma unroll 4
        for (int d4 = 0; d4 < 64; d4 += 4) {
            float4 pa[4], qb[4];
#pragma unroll
            for (int i = 0; i < 4; i++) pa[i] = *(const float4*)&Ps[ty * 4 + i][d4];
#pragma unroll
            for (int j = 0; j < 4; j++) qb[j] = *(const float4*)&Qs[tx * 4 + j][d4];
#pragma unroll
            for (int i = 0; i < 4; i++)
#pragma unroll
                for (int j = 0; j < 4; j++)
                    aq[i][j] += pa[i].x * qb[j].x + pa[i].y * qb[j].y +
                                pa[i].z * qb[j].z + pa[i].w * qb[j].w;
        }
#pragma unroll
        for (int i = 0; i < 4; i++)
#pragma unroll
            for (int j = 0; j < 4; j++)
                QPT[ty * 4 + i][tx * 4 + j] = __expf(aq[i][j]);
        __syncthreads();
#pragma unroll 8
        for (int f = 0; f < 64; f++) {
            float4 am = *(const float4*)&QPT[f][ty * 4];
            float4 bc = *(const float4*)&Cs[f][tx * 4];
            float a4[4] = {am.x, am.y, am.z, am.w};
            float b4[4] = {bc.x, bc.y, bc.z, bc.w};
#pragma unroll
            for (int i = 0; i < 4; i++)
#pragma unroll
                for (int j = 0; j < 4; j++) acc[i][j] = fmaf(a4[i], b4[j], acc[i][j]);
            if (tx == 0) {
                float kv = ksl[f];
#pragma unroll
                for (int i = 0; i < 4; i++) dacc[i] = fmaf(a4[i], kv, dacc[i]);
            }
        }
    }
    if (tx == 0) {
#pragma unroll
        for (int i = 0; i < 4; i++) Dm[ty * 4 + i] = dacc[i];
    }
    __syncthreads();
#pragma unroll
    for (int i = 0; i < 4; i++) {
        float rinv = 1.f / (Dm[ty * 4 + i] + 1e-6f);
        ushort4v o;
        o[0] = f2bf(acc[i][0] * rinv); o[1] = f2bf(acc[i][1] * rinv);
        o[2] = f2bf(acc[i][2] * rinv); o[3] = f2bf(acc[i][3] * rinv);
        *(ushort4v*)(attn + ((size_t)b * NSEQ + m0 + ty * 4 + i) * 512 + h * 64 + tx * 4) = o;
    }
}

// ---------------------------------------------------------------------------
extern "C" void kernel_launch(void* const* d_in, const int* in_sizes, int n_in,
                              void* d_out, int out_size, void* d_ws, size_t ws_size,
                              hipStream_t stream) {
    const float* x    = (const float*)d_in[0];
    const float* Wqkv = (const float*)d_in[1];
    const float* Wout = (const float*)d_in[2];
    const float* bout = (const float*)d_in[3];
    const float* proj = (const float*)d_in[4];

    float* ws    = (float*)d_ws;
    float* qkv   = ws;                                   // 25165824 f
    float* pctx  = qkv + (size_t)M_ * QKV_;              // 2097152 f
    float* pksum = pctx + (size_t)8 * 16 * 256 * 64;     // 32768 f
    float* ctx   = pksum + (size_t)8 * 16 * 256;         // 262144 f
    float* ksum  = ctx + (size_t)16 * 256 * 64;          // 4096 f
    unsigned short* xb    = (unsigned short*)(ksum + 16 * 256); // 8388608 h
    unsigned short* wqkvb = xb + (size_t)M_ * DIM_;             // 786432 h
    unsigned short* woutb = wqkvb + (size_t)QKV_ * DIM_;        // 262144 h
    unsigned short* attnb = woutb + (size_t)DIM_ * DIM_;        // 8388608 h
    float* outp  = (float*)d_out;                        // total ws ~146 MB

    // 0) fp32 -> bf16 conversions
    cvt_bf16<<<dim3((M_ * DIM_ / 8 + 255) / 256), 256, 0, stream>>>(x, xb, M_ * DIM_ / 8);
    cvt_bf16<<<dim3((QKV_ * DIM_ / 8 + 255) / 256), 256, 0, stream>>>(Wqkv, wqkvb, QKV_ * DIM_ / 8);
    cvt_bf16<<<dim3((DIM_ * DIM_ / 8 + 255) / 256), 256, 0, stream>>>(Wout, woutb, DIM_ * DIM_ / 8);
    // 1) qkv = x @ Wqkv^T   [16384 x 1536], K=512  (MFMA)
    gemm_nt_bf16<<<dim3(QKV_ / 128, M_ / 128), 256, 0, stream>>>(xb, wqkvb, nullptr, qkv, M_, QKV_, DIM_);
    // 2) context/ksum partials (k' fused)
    ctx_fused<<<dim3(4, 8, 16), 256, 0, stream>>>(qkv, proj, pctx, pksum);
    // 3) reduce partials
    reduce_parts<<<dim3((16 * 256 * 64 + 16 * 256 + 255) / 256), 256, 0, stream>>>(pctx, pksum, ctx, ksum);
    // 4) attn_out = (q' @ ctx) * D_inv (q' fused), bf16 out
    attn_fused<<<dim3(128, 16), 256, 0, stream>>>(qkv, proj, ctx, ksum, attnb);
    // 5) out = attn_out @ Wout^T + bout   [16384 x 512], K=512  (MFMA)
    gemm_nt_bf16<<<dim3(512 / 128, M_ / 128), 256, 0, stream>>>(attnb, woutb, bout, outp, M_, 512, 512);
}

// Round 3
// 234.965 us; speedup vs baseline: 3.7008x; 2.4031x over previous
//
#include <hip/hip_runtime.h>
#include <math.h>

#define B_    2
#define NSEQ  8192
#define DIM_  512
#define H_    8
#define DH_   64
#define F_    256
#define M_    (B_*NSEQ)      // 16384
#define QKV_  1536

typedef __attribute__((ext_vector_type(8))) short     short8;
typedef __attribute__((ext_vector_type(4))) float     float4v;
typedef __attribute__((ext_vector_type(8))) unsigned short ushort8v;

__device__ __forceinline__ unsigned short f2bf(float f) {
    unsigned u = __float_as_uint(f);
    u += 0x7FFFu + ((u >> 16) & 1u);   // RNE
    return (unsigned short)(u >> 16);
}
// pack two floats -> two bf16 (truncate; bias cancels in N/D ratio)
__device__ __forceinline__ unsigned pack2bf(float lo, float hi) {
    return __builtin_amdgcn_perm(__float_as_uint(hi), __float_as_uint(lo), 0x07060302);
}
__device__ __forceinline__ void glds16(const void* g, void* s) {
    __builtin_amdgcn_global_load_lds(
        (const __attribute__((address_space(1))) unsigned int*)g,
        (__attribute__((address_space(3))) unsigned int*)s, 16, 0, 0);
}

// ---------------------------------------------------------------------------
__global__ __launch_bounds__(256) void cvt_bf16(const float* __restrict__ in,
                                                unsigned short* __restrict__ out,
                                                int n8) {
    int i = blockIdx.x * 256 + threadIdx.x;
    if (i >= n8) return;
    float4 a = ((const float4*)in)[2 * i];
    float4 b = ((const float4*)in)[2 * i + 1];
    ushort8v o;
    o[0] = f2bf(a.x); o[1] = f2bf(a.y); o[2] = f2bf(a.z); o[3] = f2bf(a.w);
    o[4] = f2bf(b.x); o[5] = f2bf(b.y); o[6] = f2bf(b.z); o[7] = f2bf(b.w);
    ((ushort8v*)out)[i] = o;
}

// ---------------------------------------------------------------------------
// NT GEMM via MFMA (m97 structure), templated output dtype.
// ---------------------------------------------------------------------------
template<bool BF16OUT>
__global__ __launch_bounds__(256) void gemm_nt_mfma(const unsigned short* __restrict__ A,
                                                    const unsigned short* __restrict__ Bm,
                                                    const float* __restrict__ bias,
                                                    void* __restrict__ Cout,
                                                    int M, int N, int K) {
    __shared__ __align__(16) unsigned short As[128 * 32];
    __shared__ __align__(16) unsigned short Bs[128 * 32];
    const int t  = threadIdx.x;
    const int w  = t >> 6, l = t & 63;
    const int wm = w >> 1, wn = w & 1;
    const int m0 = blockIdx.y * 128, n0 = blockIdx.x * 128;
    const int lrow = l & 15, lkb = l >> 4;

    float4v acc[4][4];
#pragma unroll
    for (int mi = 0; mi < 4; mi++)
#pragma unroll
        for (int ni = 0; ni < 4; ni++) acc[mi][ni] = (float4v){0.f, 0.f, 0.f, 0.f};

    for (int k0 = 0; k0 < K; k0 += 32) {
        __syncthreads();
#pragma unroll
        for (int i = 0; i < 2; i++) {
            int rb8 = w * 2 + i;
            int row = rb8 * 16 + lrow;
            glds16(A + (size_t)(m0 + row) * K + k0 + lkb * 8, &As[rb8 * 512]);
            glds16(Bm + (size_t)(n0 + row) * K + k0 + lkb * 8, &Bs[rb8 * 512]);
        }
        __syncthreads();

        short8 af[4], bfr[4];
#pragma unroll
        for (int mi = 0; mi < 4; mi++)
            af[mi] = *(const short8*)&As[((wm * 4 + mi) * 64 + l) * 8];
#pragma unroll
        for (int ni = 0; ni < 4; ni++)
            bfr[ni] = *(const short8*)&Bs[((wn * 4 + ni) * 64 + l) * 8];
#pragma unroll
        for (int mi = 0; mi < 4; mi++)
#pragma unroll
            for (int ni = 0; ni < 4; ni++)
                acc[mi][ni] = __builtin_amdgcn_mfma_f32_16x16x32_bf16(
                    af[mi], bfr[ni], acc[mi][ni], 0, 0, 0);
    }

    const int q = l >> 4, c = l & 15;
#pragma unroll
    for (int mi = 0; mi < 4; mi++) {
        int row0 = m0 + wm * 64 + mi * 16 + q * 4;
#pragma unroll
        for (int ni = 0; ni < 4; ni++) {
            int col = n0 + wn * 64 + ni * 16 + c;
            float bv = bias ? bias[col] : 0.f;
#pragma unroll
            for (int r = 0; r < 4; r++) {
                float v = acc[mi][ni][r] + bv;
                if (BF16OUT) ((unsigned short*)Cout)[(size_t)(row0 + r) * N + col] = f2bf(v);
                else         ((float*)Cout)[(size_t)(row0 + r) * N + col] = v;
            }
        }
    }
}

// ---------------------------------------------------------------------------
// V transpose: qkvb V-cols -> vT[z][64][8192] bf16
// ---------------------------------------------------------------------------
__global__ __launch_bounds__(256) void vtrans(const unsigned short* __restrict__ qkvb,
                                              unsigned short* __restrict__ vT) {
    __shared__ unsigned short T[128][80];   // pad to 80 (160B rows, 16B aligned)
    const int t = threadIdx.x;
    const int n0 = blockIdx.x * 128, z = blockIdx.y;
    const int b = z >> 3, h = z & 7;
#pragma unroll
    for (int i = 0; i < 4; i++) {
        int flat = t + i * 256;            // 0..1023
        int n = flat >> 3, d8 = flat & 7;
        ushort8v v = *(const ushort8v*)(qkvb + ((size_t)b * NSEQ + n0 + n) * QKV_ + 1024 + h * 64 + d8 * 8);
        *(ushort8v*)&T[n][d8 * 8] = v;
    }
    __syncthreads();
#pragma unroll
    for (int i = 0; i < 4; i++) {
        int flat = t + i * 256;
        int d = flat >> 4, n8 = flat & 15;
        ushort8v o;
#pragma unroll
        for (int j = 0; j < 8; j++) o[j] = T[n8 * 8 + j][d];
        *(ushort8v*)(vT + ((size_t)z * 64 + d) * NSEQ + n0 + n8 * 8) = o;
    }
}

// ---------------------------------------------------------------------------
// Fused k' featuremap + split-K context via MFMA.
// Phase A: kp[n][f] = exp(K.P) (mfma, M=n64, N=f64/wave), trunc-bf16 -> KPA
//          in A-fragment order (ds_write_b64, each wave its own f-range).
// Phase B: ctx[f][dh_ext] += kp^T x vT  (ni=4 = constant-ones col -> ksum).
// partial layout: [s][z][dh_ext 80][f 256] fp32.
// ---------------------------------------------------------------------------
__global__ __launch_bounds__(256) void ctx_fused_mfma(
    const unsigned short* __restrict__ qkvb,
    const unsigned short* __restrict__ projb,
    const unsigned short* __restrict__ vT,
    float* __restrict__ partial)
{
    __shared__ __align__(16) unsigned short PB[32 * 512];   // proj B-frags (resident)
    __shared__ __align__(16) unsigned short KB[8 * 512];    // K-rows A-frags (per step)
    __shared__ __align__(16) unsigned short VB[8 * 512];    // vT B-frags (per step)
    __shared__ __align__(16) unsigned short KPA[32 * 512];  // kp A-frags
    const int t = threadIdx.x, w = t >> 6, l = t & 63;
    const int lr = l & 15, lq = l >> 4;
    const int s = blockIdx.x, z = blockIdx.y;
    const int b = z >> 3, h = z & 7;
    const int nchunk = s * 256;

    for (int idx = w; idx < 32; idx += 4) {
        int fblk = idx >> 1, kt = idx & 1;
        glds16(projb + (size_t)(fblk * 16 + lr) * 64 + kt * 32 + lq * 8, &PB[idx * 512]);
    }

    float4v acc[4][5];
#pragma unroll
    for (int mi = 0; mi < 4; mi++)
#pragma unroll
        for (int ni = 0; ni < 5; ni++) acc[mi][ni] = (float4v){0.f, 0.f, 0.f, 0.f};
    short ov = (lr == 0) ? (short)0x3F80 : (short)0;
    short8 ones = {ov, ov, ov, ov, ov, ov, ov, ov};

    for (int st = 0; st < 4; st++) {
        int nbase = nchunk + st * 64;
        __syncthreads();                       // prior-iter reads done (also PB staged, 1st iter)
        for (int idx = w; idx < 8; idx += 4) {
            int nblk = idx >> 1, kt = idx & 1;
            glds16(qkvb + ((size_t)b * NSEQ + nbase + nblk * 16 + lr) * QKV_ + 512 + h * 64 + kt * 32 + lq * 8,
                   &KB[idx * 512]);
        }
        for (int idx = w; idx < 8; idx += 4) {
            int dhb = idx >> 1, nt2 = idx & 1;
            glds16(vT + ((size_t)z * 64 + dhb * 16 + lr) * NSEQ + nbase + nt2 * 32 + lq * 8,
                   &VB[idx * 512]);
        }
        __syncthreads();

        // phase A: rows n (mi), cols f (wave quadrant w, ni)
        float4v a2[4][4];
#pragma unroll
        for (int mi = 0; mi < 4; mi++)
#pragma unroll
            for (int ni = 0; ni < 4; ni++) a2[mi][ni] = (float4v){0.f, 0.f, 0.f, 0.f};
#pragma unroll
        for (int ks = 0; ks < 2; ks++) {
            short8 ka[4], pb[4];
#pragma unroll
            for (int mi = 0; mi < 4; mi++)
                ka[mi] = *(const short8*)&KB[((mi * 2 + ks) * 64 + l) * 8];
#pragma unroll
            for (int ni = 0; ni < 4; ni++)
                pb[ni] = *(const short8*)&PB[(((w * 4 + ni) * 2 + ks) * 64 + l) * 8];
#pragma unroll
            for (int mi = 0; mi < 4; mi++)
#pragma unroll
                for (int ni = 0; ni < 4; ni++)
                    a2[mi][ni] = __builtin_amdgcn_mfma_f32_16x16x32_bf16(ka[mi], pb[ni], a2[mi][ni], 0, 0, 0);
        }
        // exp -> bf16 -> KPA (A-frag order): addr(f,n)
#pragma unroll
        for (int mi = 0; mi < 4; mi++) {
            int nb = mi * 16 + lq * 4;
            int qoff = ((nb >> 3) & 3) * 256 + (nb & 7) * 2;
            int setn = nb >> 5;
#pragma unroll
            for (int ni = 0; ni < 4; ni++) {
                int f = w * 64 + ni * 16 + lr;
                float e0 = __expf(a2[mi][ni][0]);
                float e1 = __expf(a2[mi][ni][1]);
                float e2 = __expf(a2[mi][ni][2]);
                float e3 = __expf(a2[mi][ni][3]);
                uint2 p; p.x = pack2bf(e0, e1); p.y = pack2bf(e2, e3);
                *(uint2*)((char*)KPA + (size_t)(((f >> 4) * 2 + setn) * 1024 + qoff + (f & 15) * 16)) = p;
            }
        }
        // phase B: rows f (wave w, mi), cols dh_ext (ni; ni=4 -> ksum)
#pragma unroll
        for (int ks = 0; ks < 2; ks++) {
            short8 af[4], bf[4];
#pragma unroll
            for (int mi = 0; mi < 4; mi++)
                af[mi] = *(const short8*)&KPA[(((w * 4 + mi) * 2 + ks) * 64 + l) * 8];
#pragma unroll
            for (int ni = 0; ni < 4; ni++)
                bf[ni] = *(const short8*)&VB[((ni * 2 + ks) * 64 + l) * 8];
#pragma unroll
            for (int mi = 0; mi < 4; mi++) {
#pragma unroll
                for (int ni = 0; ni < 4; ni++)
                    acc[mi][ni] = __builtin_amdgcn_mfma_f32_16x16x32_bf16(af[mi], bf[ni], acc[mi][ni], 0, 0, 0);
                acc[mi][4] = __builtin_amdgcn_mfma_f32_16x16x32_bf16(af[mi], ones, acc[mi][4], 0, 0, 0);
            }
        }
    }
    float* base = partial + (size_t)(s * 16 + z) * 80 * 256;
#pragma unroll
    for (int mi = 0; mi < 4; mi++) {
        int f0r = w * 64 + mi * 16 + lq * 4;
#pragma unroll
        for (int ni = 0; ni < 5; ni++) {
            int col = ni * 16 + lr;
#pragma unroll
            for (int r = 0; r < 4; r++)
                base[(size_t)col * 256 + f0r + r] = acc[mi][ni][r];
        }
    }
}

// ---------------------------------------------------------------------------
// Reduce split-K partials -> ctxT bf16 [z][80][256] (row 64 = ksum)
// ---------------------------------------------------------------------------
__global__ __launch_bounds__(256) void ctx_reduce(const float* __restrict__ partial,
                                                  unsigned short* __restrict__ ctxT) {
    int idx = blockIdx.x * 256 + threadIdx.x;   // 16*80*256 = 327680
    const int NC = 16 * 80 * 256;
    if (idx >= NC) return;
    float s = 0.f;
#pragma unroll
    for (int k = 0; k < 32; k++) s += partial[(size_t)k * NC + idx];
    ctxT[idx] = f2bf(s);
}

// ---------------------------------------------------------------------------
// Fused q' featuremap + (q'.ctx_ext) with D at col 64 -> bf16 attn out.
// Block: 128 m-rows x whole bh. Phase A: qp (M=f64, N=m32/wave). Phase B:
// M=m (2 mi of 16/wave), N=80 (ctxT_ext incl ksum row), K=f 64/step.
// ---------------------------------------------------------------------------
__global__ __launch_bounds__(256) void attn_fused_mfma(
    const unsigned short* __restrict__ qkvb,
    const unsigned short* __restrict__ projb,
    const unsigned short* __restrict__ ctxT,
    unsigned short* __restrict__ attnb)
{
    __shared__ __align__(16) unsigned short QB[16 * 512];   // Q rows B-frags (resident)
    __shared__ __align__(16) unsigned short PA[8 * 512];    // proj A-frags (per f-step)
    __shared__ __align__(16) unsigned short QPA[16 * 512];  // qp A-frags
    __shared__ __align__(16) unsigned short CB[10 * 512];   // ctxT B-frags (per f-step)
    const int t = threadIdx.x, w = t >> 6, l = t & 63;
    const int lr = l & 15, lq = l >> 4;
    const int m0 = blockIdx.x * 128, z = blockIdx.y;
    const int b = z >> 3, h = z & 7;

    for (int idx = w; idx < 16; idx += 4) {
        int mblk = idx >> 1, kt = idx & 1;
        glds16(qkvb + ((size_t)b * NSEQ + m0 + mblk * 16 + lr) * QKV_ + h * 64 + kt * 32 + lq * 8,
               &QB[idx * 512]);
    }
    float4v acc[2][5];
#pragma unroll
    for (int mi = 0; mi < 2; mi++)
#pragma unroll
        for (int ni = 0; ni < 5; ni++) acc[mi][ni] = (float4v){0.f, 0.f, 0.f, 0.f};

    for (int fs = 0; fs < 4; fs++) {
        int f0 = fs * 64;
        __syncthreads();
        for (int idx = w; idx < 8; idx += 4) {
            int fb = idx >> 1, kt = idx & 1;
            glds16(projb + (size_t)(f0 + fb * 16 + lr) * 64 + kt * 32 + lq * 8, &PA[idx * 512]);
        }
        for (int idx = w; idx < 10; idx += 4) {
            int dhb = idx >> 1, ft = idx & 1;
            glds16(ctxT + ((size_t)z * 80 + dhb * 16 + lr) * 256 + f0 + ft * 32 + lq * 8,
                   &CB[idx * 512]);
        }
        __syncthreads();

        // phase A: rows f (mi), cols m (wave w, ni 0..1)
        float4v a2[4][2];
#pragma unroll
        for (int mi = 0; mi < 4; mi++)
#pragma unroll
            for (int ni = 0; ni < 2; ni++) a2[mi][ni] = (float4v){0.f, 0.f, 0.f, 0.f};
#pragma unroll
        for (int ks = 0; ks < 2; ks++) {
            short8 pa[4], qb[2];
#pragma unroll
            for (int mi = 0; mi < 4; mi++)
                pa[mi] = *(const short8*)&PA[((mi * 2 + ks) * 64 + l) * 8];
#pragma unroll
            for (int ni = 0; ni < 2; ni++)
                qb[ni] = *(const short8*)&QB[(((w * 2 + ni) * 2 + ks) * 64 + l) * 8];
#pragma unroll
            for (int mi = 0; mi < 4; mi++)
#pragma unroll
                for (int ni = 0; ni < 2; ni++)
                    a2[mi][ni] = __builtin_amdgcn_mfma_f32_16x16x32_bf16(pa[mi], qb[ni], a2[mi][ni], 0, 0, 0);
        }
        // exp(scale*x) -> bf16 -> QPA (A-frag order): addr(m,f)
#pragma unroll
        for (int mi = 0; mi < 4; mi++) {
            int fb2 = mi * 16 + lq * 4;
            int qoff = ((fb2 >> 3) & 3) * 256 + (fb2 & 7) * 2;
            int setf = fb2 >> 5;
#pragma unroll
            for (int ni = 0; ni < 2; ni++) {
                int m = w * 32 + ni * 16 + lr;
                float e0 = __expf(0.125f * a2[mi][ni][0]);
                float e1 = __expf(0.125f * a2[mi][ni][1]);
                float e2 = __expf(0.125f * a2[mi][ni][2]);
                float e3 = __expf(0.125f * a2[mi][ni][3]);
                uint2 p; p.x = pack2bf(e0, e1); p.y = pack2bf(e2, e3);
                *(uint2*)((char*)QPA + (size_t)(((m >> 4) * 2 + setf) * 1024 + qoff + (m & 15) * 16)) = p;
            }
        }
        // phase B: rows m (wave w, mi 0..1), cols dh_ext
#pragma unroll
        for (int ks = 0; ks < 2; ks++) {
            short8 af[2], cb[5];
#pragma unroll
            for (int mi = 0; mi < 2; mi++)
                af[mi] = *(const short8*)&QPA[(((w * 2 + mi) * 2 + ks) * 64 + l) * 8];
#pragma unroll
            for (int ni = 0; ni < 5; ni++)
                cb[ni] = *(const short8*)&CB[((ni * 2 + ks) * 64 + l) * 8];
#pragma unroll
            for (int mi = 0; mi < 2; mi++)
#pragma unroll
                for (int ni = 0; ni < 5; ni++)
                    acc[mi][ni] = __builtin_amdgcn_mfma_f32_16x16x32_bf16(af[mi], cb[ni], acc[mi][ni], 0, 0, 0);
        }
    }
    // epilogue: D at col 64 (ni=4, c==0 lane) -> broadcast within 16-lane group
#pragma unroll
    for (int mi = 0; mi < 2; mi++) {
        int rowb = m0 + w * 32 + mi * 16 + lq * 4;
#pragma unroll
        for (int r = 0; r < 4; r++) {
            float dv = __shfl(acc[mi][4][r], (l & 48), 64);
            float rinv = 1.f / (dv + 1e-6f);
#pragma unroll
            for (int ni = 0; ni < 4; ni++)
                attnb[((size_t)b * NSEQ + rowb + r) * 512 + h * 64 + ni * 16 + lr] =
                    f2bf(acc[mi][ni][r] * rinv);
        }
    }
}

// ---------------------------------------------------------------------------
extern "C" void kernel_launch(void* const* d_in, const int* in_sizes, int n_in,
                              void* d_out, int out_size, void* d_ws, size_t ws_size,
                              hipStream_t stream) {
    const float* x    = (const float*)d_in[0];
    const float* Wqkv = (const float*)d_in[1];
    const float* Wout = (const float*)d_in[2];
    const float* bout = (const float*)d_in[3];
    const float* proj = (const float*)d_in[4];

    unsigned short* qkvb  = (unsigned short*)d_ws;                  // 25,165,824 u16
    unsigned short* vT    = qkvb + (size_t)M_ * QKV_;               // 8,388,608 u16
    float*          partial = (float*)(vT + (size_t)16 * 64 * NSEQ);// 10,485,760 f32
    unsigned short* ctxT  = (unsigned short*)(partial + (size_t)32 * 16 * 80 * 256); // 327,680 u16
    unsigned short* projb = ctxT + (size_t)16 * 80 * 256;           // 16,384 u16
    unsigned short* xb    = projb + 16384;                          // 8,388,608 u16
    unsigned short* attnb = xb;                                     // overlay (xb dead after gemm1)
    unsigned short* wqkvb = xb + (size_t)M_ * DIM_;                 // 786,432 u16
    unsigned short* woutb = wqkvb + (size_t)QKV_ * DIM_;            // 262,144 u16
    float* outp = (float*)d_out;                                    // total ws ~128.6 MB

    // 0) fp32 -> bf16
    cvt_bf16<<<dim3(4096), 256, 0, stream>>>(x, xb, M_ * DIM_ / 8);
    cvt_bf16<<<dim3(384), 256, 0, stream>>>(Wqkv, wqkvb, QKV_ * DIM_ / 8);
    cvt_bf16<<<dim3(128), 256, 0, stream>>>(Wout, woutb, DIM_ * DIM_ / 8);
    cvt_bf16<<<dim3(8), 256, 0, stream>>>(proj, projb, F_ * DH_ / 8);
    // 1) qkv = x @ Wqkv^T  (bf16 out)
    gemm_nt_mfma<true><<<dim3(QKV_ / 128, M_ / 128), 256, 0, stream>>>(xb, wqkvb, nullptr, qkvb, M_, QKV_, DIM_);
    // 2) V transpose
    vtrans<<<dim3(64, 16), 256, 0, stream>>>(qkvb, vT);
    // 3) fused k' + context partials (MFMA)
    ctx_fused_mfma<<<dim3(32, 16), 256, 0, stream>>>(qkvb, projb, vT, partial);
    // 4) reduce -> ctxT bf16 (incl. ksum row)
    ctx_reduce<<<dim3(1280), 256, 0, stream>>>(partial, ctxT);
    // 5) fused q' + attention out (MFMA), bf16
    attn_fused_mfma<<<dim3(64, 16), 256, 0, stream>>>(qkvb, projb, ctxT, attnb);
    // 6) out = attn @ Wout^T + bout
    gemm_nt_mfma<false><<<dim3(DIM_ / 128, M_ / 128), 256, 0, stream>>>(attnb, woutb, bout, outp, M_, DIM_, DIM_);
}

// Round 4
// 232.256 us; speedup vs baseline: 3.7439x; 1.0117x over previous
//
#include <hip/hip_runtime.h>
#include <math.h>

#define B_    2
#define NSEQ  8192
#define DIM_  512
#define H_    8
#define DH_   64
#define F_    256
#define M_    (B_*NSEQ)      // 16384
#define QKV_  1536

typedef __attribute__((ext_vector_type(8))) short     short8;
typedef __attribute__((ext_vector_type(4))) float     float4v;
typedef __attribute__((ext_vector_type(8))) unsigned short ushort8v;

__device__ __forceinline__ unsigned short f2bf(float f) {
    unsigned u = __float_as_uint(f);
    u += 0x7FFFu + ((u >> 16) & 1u);   // RNE
    return (unsigned short)(u >> 16);
}
// pack two floats -> two bf16 (truncate; bias cancels in N/D ratio)
__device__ __forceinline__ unsigned pack2bf(float lo, float hi) {
    return __builtin_amdgcn_perm(__float_as_uint(hi), __float_as_uint(lo), 0x07060302);
}
__device__ __forceinline__ void glds16(const void* g, void* s) {
    __builtin_amdgcn_global_load_lds(
        (const __attribute__((address_space(1))) unsigned int*)g,
        (__attribute__((address_space(3))) unsigned int*)s, 16, 0, 0);
}

// ---------------------------------------------------------------------------
// fused fp32->bf16 for all 4 inputs, one launch. Block ranges are exact
// multiples of 256 threads x 8 elems -> no bounds checks.
// ---------------------------------------------------------------------------
__global__ __launch_bounds__(256) void cvt_all(const float* __restrict__ x,
                                               const float* __restrict__ wqkv,
                                               const float* __restrict__ wout,
                                               const float* __restrict__ proj,
                                               unsigned short* __restrict__ xb,
                                               unsigned short* __restrict__ wqkvb,
                                               unsigned short* __restrict__ woutb,
                                               unsigned short* __restrict__ projb) {
    int bid = blockIdx.x;
    const float* in; unsigned short* out; int i;
    if (bid < 4096)      { in = x;    out = xb;    i = bid * 256 + threadIdx.x; }
    else if (bid < 4480) { in = wqkv; out = wqkvb; i = (bid - 4096) * 256 + threadIdx.x; }
    else if (bid < 4608) { in = wout; out = woutb; i = (bid - 4480) * 256 + threadIdx.x; }
    else                 { in = proj; out = projb; i = (bid - 4608) * 256 + threadIdx.x; }
    float4 a = ((const float4*)in)[2 * i];
    float4 b = ((const float4*)in)[2 * i + 1];
    ushort8v o;
    o[0] = f2bf(a.x); o[1] = f2bf(a.y); o[2] = f2bf(a.z); o[3] = f2bf(a.w);
    o[4] = f2bf(b.x); o[5] = f2bf(b.y); o[6] = f2bf(b.z); o[7] = f2bf(b.w);
    ((ushort8v*)out)[i] = o;
}

// ---------------------------------------------------------------------------
// v2 NT GEMM: block 256x128, 4 waves 2x2, wave tile 128x64 (8x4 mfma grid),
// BK=64. 42.7 FLOP/LDS-byte (vs 32 for 64x64 wave tile) + half the barriers.
// LDS 48 KB; launch_bounds(256,2) -> 2 blocks/CU VGPR-wise.
// ---------------------------------------------------------------------------
template<bool BF16OUT>
__global__ __launch_bounds__(256, 2) void gemm_nt_v2(const unsigned short* __restrict__ A,
                                                     const unsigned short* __restrict__ Bm,
                                                     const float* __restrict__ bias,
                                                     void* __restrict__ Cout,
                                                     int M, int N, int K) {
    __shared__ __align__(16) unsigned short As[256 * 64];   // 32 slabs of 512 elems
    __shared__ __align__(16) unsigned short Bs[128 * 64];   // 16 slabs
    const int t  = threadIdx.x;
    const int w  = t >> 6, l = t & 63;
    const int wm = w >> 1, wn = w & 1;
    const int m0 = blockIdx.y * 256, n0 = blockIdx.x * 128;
    const int lr = l & 15, lq = l >> 4;

    float4v acc[8][4];
#pragma unroll
    for (int mi = 0; mi < 8; mi++)
#pragma unroll
        for (int ni = 0; ni < 4; ni++) acc[mi][ni] = (float4v){0.f, 0.f, 0.f, 0.f};

    for (int k0 = 0; k0 < K; k0 += 64) {
        __syncthreads();
        // stage A: slabs 0..31 (rowblk = idx>>1, ks = idx&1); B: slabs 32..47
#pragma unroll
        for (int ii = 0; ii < 12; ii++) {
            int idx = w + ii * 4;
            if (idx < 32) {
                glds16(A + (size_t)(m0 + (idx >> 1) * 16 + lr) * K + k0 + (idx & 1) * 32 + lq * 8,
                       &As[idx * 512]);
            } else {
                int j = idx - 32;
                glds16(Bm + (size_t)(n0 + (j >> 1) * 16 + lr) * K + k0 + (j & 1) * 32 + lq * 8,
                       &Bs[j * 512]);
            }
        }
        __syncthreads();

#pragma unroll
        for (int ks = 0; ks < 2; ks++) {
            short8 af[8], bfr[4];
#pragma unroll
            for (int mi = 0; mi < 8; mi++)
                af[mi] = *(const short8*)&As[(((wm * 8 + mi) * 2 + ks) * 64 + l) * 8];
#pragma unroll
            for (int ni = 0; ni < 4; ni++)
                bfr[ni] = *(const short8*)&Bs[(((wn * 4 + ni) * 2 + ks) * 64 + l) * 8];
#pragma unroll
            for (int mi = 0; mi < 8; mi++)
#pragma unroll
                for (int ni = 0; ni < 4; ni++)
                    acc[mi][ni] = __builtin_amdgcn_mfma_f32_16x16x32_bf16(
                        af[mi], bfr[ni], acc[mi][ni], 0, 0, 0);
        }
    }

    const int q = l >> 4, c = l & 15;
#pragma unroll
    for (int mi = 0; mi < 8; mi++) {
        int row0 = m0 + wm * 128 + mi * 16 + q * 4;
#pragma unroll
        for (int ni = 0; ni < 4; ni++) {
            int col = n0 + wn * 64 + ni * 16 + c;
            float bv = bias ? bias[col] : 0.f;
#pragma unroll
            for (int r = 0; r < 4; r++) {
                float v = acc[mi][ni][r] + bv;
                if (BF16OUT) ((unsigned short*)Cout)[(size_t)(row0 + r) * N + col] = f2bf(v);
                else         ((float*)Cout)[(size_t)(row0 + r) * N + col] = v;
            }
        }
    }
}

// ---------------------------------------------------------------------------
// v1 NT GEMM (m97 structure, 128x128): kept for gemm2 (N=512 -> grid 512,
// 2 blocks/CU; the 256-row tile would leave only 1 block/CU there).
// ---------------------------------------------------------------------------
template<bool BF16OUT>
__global__ __launch_bounds__(256) void gemm_nt_mfma(const unsigned short* __restrict__ A,
                                                    const unsigned short* __restrict__ Bm,
                                                    const float* __restrict__ bias,
                                                    void* __restrict__ Cout,
                                                    int M, int N, int K) {
    __shared__ __align__(16) unsigned short As[128 * 32];
    __shared__ __align__(16) unsigned short Bs[128 * 32];
    const int t  = threadIdx.x;
    const int w  = t >> 6, l = t & 63;
    const int wm = w >> 1, wn = w & 1;
    const int m0 = blockIdx.y * 128, n0 = blockIdx.x * 128;
    const int lrow = l & 15, lkb = l >> 4;

    float4v acc[4][4];
#pragma unroll
    for (int mi = 0; mi < 4; mi++)
#pragma unroll
        for (int ni = 0; ni < 4; ni++) acc[mi][ni] = (float4v){0.f, 0.f, 0.f, 0.f};

    for (int k0 = 0; k0 < K; k0 += 32) {
        __syncthreads();
#pragma unroll
        for (int i = 0; i < 2; i++) {
            int rb8 = w * 2 + i;
            int row = rb8 * 16 + lrow;
            glds16(A + (size_t)(m0 + row) * K + k0 + lkb * 8, &As[rb8 * 512]);
            glds16(Bm + (size_t)(n0 + row) * K + k0 + lkb * 8, &Bs[rb8 * 512]);
        }
        __syncthreads();

        short8 af[4], bfr[4];
#pragma unroll
        for (int mi = 0; mi < 4; mi++)
            af[mi] = *(const short8*)&As[((wm * 4 + mi) * 64 + l) * 8];
#pragma unroll
        for (int ni = 0; ni < 4; ni++)
            bfr[ni] = *(const short8*)&Bs[((wn * 4 + ni) * 64 + l) * 8];
#pragma unroll
        for (int mi = 0; mi < 4; mi++)
#pragma unroll
            for (int ni = 0; ni < 4; ni++)
                acc[mi][ni] = __builtin_amdgcn_mfma_f32_16x16x32_bf16(
                    af[mi], bfr[ni], acc[mi][ni], 0, 0, 0);
    }

    const int q = l >> 4, c = l & 15;
#pragma unroll
    for (int mi = 0; mi < 4; mi++) {
        int row0 = m0 + wm * 64 + mi * 16 + q * 4;
#pragma unroll
        for (int ni = 0; ni < 4; ni++) {
            int col = n0 + wn * 64 + ni * 16 + c;
            float bv = bias ? bias[col] : 0.f;
#pragma unroll
            for (int r = 0; r < 4; r++) {
                float v = acc[mi][ni][r] + bv;
                if (BF16OUT) ((unsigned short*)Cout)[(size_t)(row0 + r) * N + col] = f2bf(v);
                else         ((float*)Cout)[(size_t)(row0 + r) * N + col] = v;
            }
        }
    }
}

// ---------------------------------------------------------------------------
// V transpose: qkvb V-cols -> vT[z][64][8192] bf16
// ---------------------------------------------------------------------------
__global__ __launch_bounds__(256) void vtrans(const unsigned short* __restrict__ qkvb,
                                              unsigned short* __restrict__ vT) {
    __shared__ unsigned short T[128][80];
    const int t = threadIdx.x;
    const int n0 = blockIdx.x * 128, z = blockIdx.y;
    const int b = z >> 3, h = z & 7;
#pragma unroll
    for (int i = 0; i < 4; i++) {
        int flat = t + i * 256;
        int n = flat >> 3, d8 = flat & 7;
        ushort8v v = *(const ushort8v*)(qkvb + ((size_t)b * NSEQ + n0 + n) * QKV_ + 1024 + h * 64 + d8 * 8);
        *(ushort8v*)&T[n][d8 * 8] = v;
    }
    __syncthreads();
#pragma unroll
    for (int i = 0; i < 4; i++) {
        int flat = t + i * 256;
        int d = flat >> 4, n8 = flat & 15;
        ushort8v o;
#pragma unroll
        for (int j = 0; j < 8; j++) o[j] = T[n8 * 8 + j][d];
        *(ushort8v*)(vT + ((size_t)z * 64 + d) * NSEQ + n0 + n8 * 8) = o;
    }
}

// ---------------------------------------------------------------------------
// Fused k' featuremap + split-K context via MFMA.
// ---------------------------------------------------------------------------
__global__ __launch_bounds__(256) void ctx_fused_mfma(
    const unsigned short* __restrict__ qkvb,
    const unsigned short* __restrict__ projb,
    const unsigned short* __restrict__ vT,
    float* __restrict__ partial)
{
    __shared__ __align__(16) unsigned short PB[32 * 512];
    __shared__ __align__(16) unsigned short KB[8 * 512];
    __shared__ __align__(16) unsigned short VB[8 * 512];
    __shared__ __align__(16) unsigned short KPA[32 * 512];
    const int t = threadIdx.x, w = t >> 6, l = t & 63;
    const int lr = l & 15, lq = l >> 4;
    const int s = blockIdx.x, z = blockIdx.y;
    const int b = z >> 3, h = z & 7;
    const int nchunk = s * 256;

    for (int idx = w; idx < 32; idx += 4) {
        int fblk = idx >> 1, kt = idx & 1;
        glds16(projb + (size_t)(fblk * 16 + lr) * 64 + kt * 32 + lq * 8, &PB[idx * 512]);
    }

    float4v acc[4][5];
#pragma unroll
    for (int mi = 0; mi < 4; mi++)
#pragma unroll
        for (int ni = 0; ni < 5; ni++) acc[mi][ni] = (float4v){0.f, 0.f, 0.f, 0.f};
    short ov = (lr == 0) ? (short)0x3F80 : (short)0;
    short8 ones = {ov, ov, ov, ov, ov, ov, ov, ov};

    for (int st = 0; st < 4; st++) {
        int nbase = nchunk + st * 64;
        __syncthreads();
        for (int idx = w; idx < 8; idx += 4) {
            int nblk = idx >> 1, kt = idx & 1;
            glds16(qkvb + ((size_t)b * NSEQ + nbase + nblk * 16 + lr) * QKV_ + 512 + h * 64 + kt * 32 + lq * 8,
                   &KB[idx * 512]);
        }
        for (int idx = w; idx < 8; idx += 4) {
            int dhb = idx >> 1, nt2 = idx & 1;
            glds16(vT + ((size_t)z * 64 + dhb * 16 + lr) * NSEQ + nbase + nt2 * 32 + lq * 8,
                   &VB[idx * 512]);
        }
        __syncthreads();

        float4v a2[4][4];
#pragma unroll
        for (int mi = 0; mi < 4; mi++)
#pragma unroll
            for (int ni = 0; ni < 4; ni++) a2[mi][ni] = (float4v){0.f, 0.f, 0.f, 0.f};
#pragma unroll
        for (int ks = 0; ks < 2; ks++) {
            short8 ka[4], pb[4];
#pragma unroll
            for (int mi = 0; mi < 4; mi++)
                ka[mi] = *(const short8*)&KB[((mi * 2 + ks) * 64 + l) * 8];
#pragma unroll
            for (int ni = 0; ni < 4; ni++)
                pb[ni] = *(const short8*)&PB[(((w * 4 + ni) * 2 + ks) * 64 + l) * 8];
#pragma unroll
            for (int mi = 0; mi < 4; mi++)
#pragma unroll
                for (int ni = 0; ni < 4; ni++)
                    a2[mi][ni] = __builtin_amdgcn_mfma_f32_16x16x32_bf16(ka[mi], pb[ni], a2[mi][ni], 0, 0, 0);
        }
#pragma unroll
        for (int mi = 0; mi < 4; mi++) {
            int nb = mi * 16 + lq * 4;
            int qoff = ((nb >> 3) & 3) * 256 + (nb & 7) * 2;
            int setn = nb >> 5;
#pragma unroll
            for (int ni = 0; ni < 4; ni++) {
                int f = w * 64 + ni * 16 + lr;
                float e0 = __expf(a2[mi][ni][0]);
                float e1 = __expf(a2[mi][ni][1]);
                float e2 = __expf(a2[mi][ni][2]);
                float e3 = __expf(a2[mi][ni][3]);
                uint2 p; p.x = pack2bf(e0, e1); p.y = pack2bf(e2, e3);
                *(uint2*)((char*)KPA + (size_t)(((f >> 4) * 2 + setn) * 1024 + qoff + (f & 15) * 16)) = p;
            }
        }
#pragma unroll
        for (int ks = 0; ks < 2; ks++) {
            short8 af[4], bf[4];
#pragma unroll
            for (int mi = 0; mi < 4; mi++)
                af[mi] = *(const short8*)&KPA[(((w * 4 + mi) * 2 + ks) * 64 + l) * 8];
#pragma unroll
            for (int ni = 0; ni < 4; ni++)
                bf[ni] = *(const short8*)&VB[((ni * 2 + ks) * 64 + l) * 8];
#pragma unroll
            for (int mi = 0; mi < 4; mi++) {
#pragma unroll
                for (int ni = 0; ni < 4; ni++)
                    acc[mi][ni] = __builtin_amdgcn_mfma_f32_16x16x32_bf16(af[mi], bf[ni], acc[mi][ni], 0, 0, 0);
                acc[mi][4] = __builtin_amdgcn_mfma_f32_16x16x32_bf16(af[mi], ones, acc[mi][4], 0, 0, 0);
            }
        }
    }
    float* base = partial + (size_t)(s * 16 + z) * 80 * 256;
#pragma unroll
    for (int mi = 0; mi < 4; mi++) {
        int f0r = w * 64 + mi * 16 + lq * 4;
#pragma unroll
        for (int ni = 0; ni < 5; ni++) {
            int col = ni * 16 + lr;
#pragma unroll
            for (int r = 0; r < 4; r++)
                base[(size_t)col * 256 + f0r + r] = acc[mi][ni][r];
        }
    }
}

// ---------------------------------------------------------------------------
__global__ __launch_bounds__(256) void ctx_reduce(const float* __restrict__ partial,
                                                  unsigned short* __restrict__ ctxT) {
    int idx = blockIdx.x * 256 + threadIdx.x;
    const int NC = 16 * 80 * 256;
    if (idx >= NC) return;
    float s = 0.f;
#pragma unroll
    for (int k = 0; k < 32; k++) s += partial[(size_t)k * NC + idx];
    ctxT[idx] = f2bf(s);
}

// ---------------------------------------------------------------------------
// Fused q' featuremap + (q'.ctx_ext) with D at col 64 -> bf16 attn out.
// ---------------------------------------------------------------------------
__global__ __launch_bounds__(256) void attn_fused_mfma(
    const unsigned short* __restrict__ qkvb,
    const unsigned short* __restrict__ projb,
    const unsigned short* __restrict__ ctxT,
    unsigned short* __restrict__ attnb)
{
    __shared__ __align__(16) unsigned short QB[16 * 512];
    __shared__ __align__(16) unsigned short PA[8 * 512];
    __shared__ __align__(16) unsigned short QPA[16 * 512];
    __shared__ __align__(16) unsigned short CB[10 * 512];
    const int t = threadIdx.x, w = t >> 6, l = t & 63;
    const int lr = l & 15, lq = l >> 4;
    const int m0 = blockIdx.x * 128, z = blockIdx.y;
    const int b = z >> 3, h = z & 7;

    for (int idx = w; idx < 16; idx += 4) {
        int mblk = idx >> 1, kt = idx & 1;
        glds16(qkvb + ((size_t)b * NSEQ + m0 + mblk * 16 + lr) * QKV_ + h * 64 + kt * 32 + lq * 8,
               &QB[idx * 512]);
    }
    float4v acc[2][5];
#pragma unroll
    for (int mi = 0; mi < 2; mi++)
#pragma unroll
        for (int ni = 0; ni < 5; ni++) acc[mi][ni] = (float4v){0.f, 0.f, 0.f, 0.f};

    for (int fs = 0; fs < 4; fs++) {
        int f0 = fs * 64;
        __syncthreads();
        for (int idx = w; idx < 8; idx += 4) {
            int fb = idx >> 1, kt = idx & 1;
            glds16(projb + (size_t)(f0 + fb * 16 + lr) * 64 + kt * 32 + lq * 8, &PA[idx * 512]);
        }
        for (int idx = w; idx < 10; idx += 4) {
            int dhb = idx >> 1, ft = idx & 1;
            glds16(ctxT + ((size_t)z * 80 + dhb * 16 + lr) * 256 + f0 + ft * 32 + lq * 8,
                   &CB[idx * 512]);
        }
        __syncthreads();

        float4v a2[4][2];
#pragma unroll
        for (int mi = 0; mi < 4; mi++)
#pragma unroll
            for (int ni = 0; ni < 2; ni++) a2[mi][ni] = (float4v){0.f, 0.f, 0.f, 0.f};
#pragma unroll
        for (int ks = 0; ks < 2; ks++) {
            short8 pa[4], qb[2];
#pragma unroll
            for (int mi = 0; mi < 4; mi++)
                pa[mi] = *(const short8*)&PA[((mi * 2 + ks) * 64 + l) * 8];
#pragma unroll
            for (int ni = 0; ni < 2; ni++)
                qb[ni] = *(const short8*)&QB[(((w * 2 + ni) * 2 + ks) * 64 + l) * 8];
#pragma unroll
            for (int mi = 0; mi < 4; mi++)
#pragma unroll
                for (int ni = 0; ni < 2; ni++)
                    a2[mi][ni] = __builtin_amdgcn_mfma_f32_16x16x32_bf16(pa[mi], qb[ni], a2[mi][ni], 0, 0, 0);
        }
#pragma unroll
        for (int mi = 0; mi < 4; mi++) {
            int fb2 = mi * 16 + lq * 4;
            int qoff = ((fb2 >> 3) & 3) * 256 + (fb2 & 7) * 2;
            int setf = fb2 >> 5;
#pragma unroll
            for (int ni = 0; ni < 2; ni++) {
                int m = w * 32 + ni * 16 + lr;
                float e0 = __expf(0.125f * a2[mi][ni][0]);
                float e1 = __expf(0.125f * a2[mi][ni][1]);
                float e2 = __expf(0.125f * a2[mi][ni][2]);
                float e3 = __expf(0.125f * a2[mi][ni][3]);
                uint2 p; p.x = pack2bf(e0, e1); p.y = pack2bf(e2, e3);
                *(uint2*)((char*)QPA + (size_t)(((m >> 4) * 2 + setf) * 1024 + qoff + (m & 15) * 16)) = p;
            }
        }
#pragma unroll
        for (int ks = 0; ks < 2; ks++) {
            short8 af[2], cb[5];
#pragma unroll
            for (int mi = 0; mi < 2; mi++)
                af[mi] = *(const short8*)&QPA[(((w * 2 + mi) * 2 + ks) * 64 + l) * 8];
#pragma unroll
            for (int ni = 0; ni < 5; ni++)
                cb[ni] = *(const short8*)&CB[((ni * 2 + ks) * 64 + l) * 8];
#pragma unroll
            for (int mi = 0; mi < 2; mi++)
#pragma unroll
                for (int ni = 0; ni < 5; ni++)
                    acc[mi][ni] = __builtin_amdgcn_mfma_f32_16x16x32_bf16(af[mi], cb[ni], acc[mi][ni], 0, 0, 0);
        }
    }
#pragma unroll
    for (int mi = 0; mi < 2; mi++) {
        int rowb = m0 + w * 32 + mi * 16 + lq * 4;
#pragma unroll
        for (int r = 0; r < 4; r++) {
            float dv = __shfl(acc[mi][4][r], (l & 48), 64);
            float rinv = 1.f / (dv + 1e-6f);
#pragma unroll
            for (int ni = 0; ni < 4; ni++)
                attnb[((size_t)b * NSEQ + rowb + r) * 512 + h * 64 + ni * 16 + lr] =
                    f2bf(acc[mi][ni][r] * rinv);
        }
    }
}

// ---------------------------------------------------------------------------
extern "C" void kernel_launch(void* const* d_in, const int* in_sizes, int n_in,
                              void* d_out, int out_size, void* d_ws, size_t ws_size,
                              hipStream_t stream) {
    const float* x    = (const float*)d_in[0];
    const float* Wqkv = (const float*)d_in[1];
    const float* Wout = (const float*)d_in[2];
    const float* bout = (const float*)d_in[3];
    const float* proj = (const float*)d_in[4];

    unsigned short* qkvb  = (unsigned short*)d_ws;                  // 25,165,824 u16
    unsigned short* vT    = qkvb + (size_t)M_ * QKV_;               // 8,388,608 u16
    float*          partial = (float*)(vT + (size_t)16 * 64 * NSEQ);// 10,485,760 f32
    unsigned short* ctxT  = (unsigned short*)(partial + (size_t)32 * 16 * 80 * 256); // 327,680 u16
    unsigned short* projb = ctxT + (size_t)16 * 80 * 256;           // 16,384 u16
    unsigned short* xb    = projb + 16384;                          // 8,388,608 u16
    unsigned short* attnb = xb;                                     // overlay (xb dead after gemm1)
    unsigned short* wqkvb = xb + (size_t)M_ * DIM_;                 // 786,432 u16
    unsigned short* woutb = wqkvb + (size_t)QKV_ * DIM_;            // 262,144 u16
    float* outp = (float*)d_out;                                    // total ws ~128.6 MB

    // 0) fp32 -> bf16 (single launch, exact block ranges)
    cvt_all<<<dim3(4616), 256, 0, stream>>>(x, Wqkv, Wout, proj, xb, wqkvb, woutb, projb);
    // 1) qkv = x @ Wqkv^T  (bf16 out) — v2 tile 256x128, BK=64
    gemm_nt_v2<true><<<dim3(QKV_ / 128, M_ / 256), 256, 0, stream>>>(xb, wqkvb, nullptr, qkvb, M_, QKV_, DIM_);
    // 2) V transpose
    vtrans<<<dim3(64, 16), 256, 0, stream>>>(qkvb, vT);
    // 3) fused k' + context partials (MFMA)
    ctx_fused_mfma<<<dim3(32, 16), 256, 0, stream>>>(qkvb, projb, vT, partial);
    // 4) reduce -> ctxT bf16 (incl. ksum row)
    ctx_reduce<<<dim3(1280), 256, 0, stream>>>(partial, ctxT);
    // 5) fused q' + attention out (MFMA), bf16
    attn_fused_mfma<<<dim3(64, 16), 256, 0, stream>>>(qkvb, projb, ctxT, attnb);
    // 6) out = attn @ Wout^T + bout — v1 tile 128x128 (grid 512 = 2/CU)
    gemm_nt_mfma<false><<<dim3(DIM_ / 128, M_ / 128), 256, 0, stream>>>(attnb, woutb, bout, outp, M_, DIM_, DIM_);
}

// Round 5
// 229.721 us; speedup vs baseline: 3.7853x; 1.0110x over previous
//
#include <hip/hip_runtime.h>
#include <math.h>

#define B_    2
#define NSEQ  8192
#define DIM_  512
#define H_    8
#define DH_   64
#define F_    256
#define M_    (B_*NSEQ)      // 16384
#define QKV_  1536

typedef __attribute__((ext_vector_type(8))) short     short8;
typedef __attribute__((ext_vector_type(4))) float     float4v;
typedef __attribute__((ext_vector_type(8))) unsigned short ushort8v;

__device__ __forceinline__ unsigned short f2bf(float f) {
    unsigned u = __float_as_uint(f);
    u += 0x7FFFu + ((u >> 16) & 1u);   // RNE
    return (unsigned short)(u >> 16);
}
// pack two floats -> two bf16 (truncate; bias cancels in N/D ratio)
__device__ __forceinline__ unsigned pack2bf(float lo, float hi) {
    return __builtin_amdgcn_perm(__float_as_uint(hi), __float_as_uint(lo), 0x07060302);
}
__device__ __forceinline__ void glds16(const void* g, void* s) {
    __builtin_amdgcn_global_load_lds(
        (const __attribute__((address_space(1))) unsigned int*)g,
        (__attribute__((address_space(3))) unsigned int*)s, 16, 0, 0);
}

// ---------------------------------------------------------------------------
// fused fp32->bf16 for all 4 inputs, one launch.
// ---------------------------------------------------------------------------
__global__ __launch_bounds__(256) void cvt_all(const float* __restrict__ x,
                                               const float* __restrict__ wqkv,
                                               const float* __restrict__ wout,
                                               const float* __restrict__ proj,
                                               unsigned short* __restrict__ xb,
                                               unsigned short* __restrict__ wqkvb,
                                               unsigned short* __restrict__ woutb,
                                               unsigned short* __restrict__ projb) {
    int bid = blockIdx.x;
    const float* in; unsigned short* out; int i;
    if (bid < 4096)      { in = x;    out = xb;    i = bid * 256 + threadIdx.x; }
    else if (bid < 4480) { in = wqkv; out = wqkvb; i = (bid - 4096) * 256 + threadIdx.x; }
    else if (bid < 4608) { in = wout; out = woutb; i = (bid - 4480) * 256 + threadIdx.x; }
    else                 { in = proj; out = projb; i = (bid - 4608) * 256 + threadIdx.x; }
    float4 a = ((const float4*)in)[2 * i];
    float4 b = ((const float4*)in)[2 * i + 1];
    ushort8v o;
    o[0] = f2bf(a.x); o[1] = f2bf(a.y); o[2] = f2bf(a.z); o[3] = f2bf(a.w);
    o[4] = f2bf(b.x); o[5] = f2bf(b.y); o[6] = f2bf(b.z); o[7] = f2bf(b.w);
    ((ushort8v*)out)[i] = o;
}

// ---------------------------------------------------------------------------
// Pipelined NT GEMM: 128x128 tile, BK=32, ping-pong LDS (2x16KB), ONE barrier
// per K-iter. glds(k+1) is issued before MFMA(k), so the vmcnt(0) drain at the
// barrier is mostly pre-satisfied (vs m97's 2-barrier full stall).
// Wave tile 64x64 = 4x4 mfma_f32_16x16x32_bf16. LDS in fragment order:
// slab s (16 rows x 32 k) read by lane l at slab_base + l*8 elems.
// ---------------------------------------------------------------------------
template<bool BF16OUT>
__global__ __launch_bounds__(256) void gemm_nt_pp(const unsigned short* __restrict__ A,
                                                  const unsigned short* __restrict__ Bm,
                                                  const float* __restrict__ bias,
                                                  void* __restrict__ Cout,
                                                  int M, int N, int K) {
    __shared__ __align__(16) unsigned short As[2][128 * 32];
    __shared__ __align__(16) unsigned short Bs[2][128 * 32];
    const int t  = threadIdx.x;
    const int w  = t >> 6, l = t & 63;
    const int wm = w >> 1, wn = w & 1;
    const int m0 = blockIdx.y * 128, n0 = blockIdx.x * 128;
    const int lr = l & 15, lq = l >> 4;

    float4v acc[4][4];
#pragma unroll
    for (int mi = 0; mi < 4; mi++)
#pragma unroll
        for (int ni = 0; ni < 4; ni++) acc[mi][ni] = (float4v){0.f, 0.f, 0.f, 0.f};

    auto stage = [&](int buf, int k0) {
#pragma unroll
        for (int i = 0; i < 2; i++) {
            int rb8 = w * 2 + i;
            int row = rb8 * 16 + lr;
            glds16(A + (size_t)(m0 + row) * K + k0 + lq * 8, &As[buf][rb8 * 512]);
            glds16(Bm + (size_t)(n0 + row) * K + k0 + lq * 8, &Bs[buf][rb8 * 512]);
        }
    };

    const int nk = K >> 5;
    stage(0, 0);
    __syncthreads();                       // full drain once (prologue)

    for (int k = 0; k < nk; k++) {
        const int cur = k & 1;
        if (k + 1 < nk) stage(cur ^ 1, (k + 1) << 5);   // in flight across MFMA

        short8 af[4], bfr[4];
#pragma unroll
        for (int mi = 0; mi < 4; mi++)
            af[mi] = *(const short8*)&As[cur][((wm * 4 + mi) * 64 + l) * 8];
#pragma unroll
        for (int ni = 0; ni < 4; ni++)
            bfr[ni] = *(const short8*)&Bs[cur][((wn * 4 + ni) * 64 + l) * 8];
#pragma unroll
        for (int mi = 0; mi < 4; mi++)
#pragma unroll
            for (int ni = 0; ni < 4; ni++)
                acc[mi][ni] = __builtin_amdgcn_mfma_f32_16x16x32_bf16(
                    af[mi], bfr[ni], acc[mi][ni], 0, 0, 0);

        if (k + 1 < nk) __syncthreads();   // one barrier/iter: reads(k) retired,
                                           // glds(k+1) drained (mostly overlapped)
    }

    const int q = l >> 4, c = l & 15;      // C/D: col=lane&15, row=quad*4+reg
#pragma unroll
    for (int mi = 0; mi < 4; mi++) {
        int row0 = m0 + wm * 64 + mi * 16 + q * 4;
#pragma unroll
        for (int ni = 0; ni < 4; ni++) {
            int col = n0 + wn * 64 + ni * 16 + c;
            float bv = bias ? bias[col] : 0.f;
#pragma unroll
            for (int r = 0; r < 4; r++) {
                float v = acc[mi][ni][r] + bv;
                if (BF16OUT) ((unsigned short*)Cout)[(size_t)(row0 + r) * N + col] = f2bf(v);
                else         ((float*)Cout)[(size_t)(row0 + r) * N + col] = v;
            }
        }
    }
}

// ---------------------------------------------------------------------------
// V transpose: qkvb V-cols -> vT[z][64][8192] bf16
// ---------------------------------------------------------------------------
__global__ __launch_bounds__(256) void vtrans(const unsigned short* __restrict__ qkvb,
                                              unsigned short* __restrict__ vT) {
    __shared__ unsigned short T[128][80];
    const int t = threadIdx.x;
    const int n0 = blockIdx.x * 128, z = blockIdx.y;
    const int b = z >> 3, h = z & 7;
#pragma unroll
    for (int i = 0; i < 4; i++) {
        int flat = t + i * 256;
        int n = flat >> 3, d8 = flat & 7;
        ushort8v v = *(const ushort8v*)(qkvb + ((size_t)b * NSEQ + n0 + n) * QKV_ + 1024 + h * 64 + d8 * 8);
        *(ushort8v*)&T[n][d8 * 8] = v;
    }
    __syncthreads();
#pragma unroll
    for (int i = 0; i < 4; i++) {
        int flat = t + i * 256;
        int d = flat >> 4, n8 = flat & 15;
        ushort8v o;
#pragma unroll
        for (int j = 0; j < 8; j++) o[j] = T[n8 * 8 + j][d];
        *(ushort8v*)(vT + ((size_t)z * 64 + d) * NSEQ + n0 + n8 * 8) = o;
    }
}

// ---------------------------------------------------------------------------
// Fused k' featuremap + split-K context via MFMA.
// ---------------------------------------------------------------------------
__global__ __launch_bounds__(256) void ctx_fused_mfma(
    const unsigned short* __restrict__ qkvb,
    const unsigned short* __restrict__ projb,
    const unsigned short* __restrict__ vT,
    float* __restrict__ partial)
{
    __shared__ __align__(16) unsigned short PB[32 * 512];
    __shared__ __align__(16) unsigned short KB[8 * 512];
    __shared__ __align__(16) unsigned short VB[8 * 512];
    __shared__ __align__(16) unsigned short KPA[32 * 512];
    const int t = threadIdx.x, w = t >> 6, l = t & 63;
    const int lr = l & 15, lq = l >> 4;
    const int s = blockIdx.x, z = blockIdx.y;
    const int b = z >> 3, h = z & 7;
    const int nchunk = s * 256;

    for (int idx = w; idx < 32; idx += 4) {
        int fblk = idx >> 1, kt = idx & 1;
        glds16(projb + (size_t)(fblk * 16 + lr) * 64 + kt * 32 + lq * 8, &PB[idx * 512]);
    }

    float4v acc[4][5];
#pragma unroll
    for (int mi = 0; mi < 4; mi++)
#pragma unroll
        for (int ni = 0; ni < 5; ni++) acc[mi][ni] = (float4v){0.f, 0.f, 0.f, 0.f};
    short ov = (lr == 0) ? (short)0x3F80 : (short)0;
    short8 ones = {ov, ov, ov, ov, ov, ov, ov, ov};

    for (int st = 0; st < 4; st++) {
        int nbase = nchunk + st * 64;
        __syncthreads();
        for (int idx = w; idx < 8; idx += 4) {
            int nblk = idx >> 1, kt = idx & 1;
            glds16(qkvb + ((size_t)b * NSEQ + nbase + nblk * 16 + lr) * QKV_ + 512 + h * 64 + kt * 32 + lq * 8,
                   &KB[idx * 512]);
        }
        for (int idx = w; idx < 8; idx += 4) {
            int dhb = idx >> 1, nt2 = idx & 1;
            glds16(vT + ((size_t)z * 64 + dhb * 16 + lr) * NSEQ + nbase + nt2 * 32 + lq * 8,
                   &VB[idx * 512]);
        }
        __syncthreads();

        float4v a2[4][4];
#pragma unroll
        for (int mi = 0; mi < 4; mi++)
#pragma unroll
            for (int ni = 0; ni < 4; ni++) a2[mi][ni] = (float4v){0.f, 0.f, 0.f, 0.f};
#pragma unroll
        for (int ks = 0; ks < 2; ks++) {
            short8 ka[4], pb[4];
#pragma unroll
            for (int mi = 0; mi < 4; mi++)
                ka[mi] = *(const short8*)&KB[((mi * 2 + ks) * 64 + l) * 8];
#pragma unroll
            for (int ni = 0; ni < 4; ni++)
                pb[ni] = *(const short8*)&PB[(((w * 4 + ni) * 2 + ks) * 64 + l) * 8];
#pragma unroll
            for (int mi = 0; mi < 4; mi++)
#pragma unroll
                for (int ni = 0; ni < 4; ni++)
                    a2[mi][ni] = __builtin_amdgcn_mfma_f32_16x16x32_bf16(ka[mi], pb[ni], a2[mi][ni], 0, 0, 0);
        }
#pragma unroll
        for (int mi = 0; mi < 4; mi++) {
            int nb = mi * 16 + lq * 4;
            int qoff = ((nb >> 3) & 3) * 256 + (nb & 7) * 2;
            int setn = nb >> 5;
#pragma unroll
            for (int ni = 0; ni < 4; ni++) {
                int f = w * 64 + ni * 16 + lr;
                float e0 = __expf(a2[mi][ni][0]);
                float e1 = __expf(a2[mi][ni][1]);
                float e2 = __expf(a2[mi][ni][2]);
                float e3 = __expf(a2[mi][ni][3]);
                uint2 p; p.x = pack2bf(e0, e1); p.y = pack2bf(e2, e3);
                *(uint2*)((char*)KPA + (size_t)(((f >> 4) * 2 + setn) * 1024 + qoff + (f & 15) * 16)) = p;
            }
        }
#pragma unroll
        for (int ks = 0; ks < 2; ks++) {
            short8 af[4], bf[4];
#pragma unroll
            for (int mi = 0; mi < 4; mi++)
                af[mi] = *(const short8*)&KPA[(((w * 4 + mi) * 2 + ks) * 64 + l) * 8];
#pragma unroll
            for (int ni = 0; ni < 4; ni++)
                bf[ni] = *(const short8*)&VB[((ni * 2 + ks) * 64 + l) * 8];
#pragma unroll
            for (int mi = 0; mi < 4; mi++) {
#pragma unroll
                for (int ni = 0; ni < 4; ni++)
                    acc[mi][ni] = __builtin_amdgcn_mfma_f32_16x16x32_bf16(af[mi], bf[ni], acc[mi][ni], 0, 0, 0);
                acc[mi][4] = __builtin_amdgcn_mfma_f32_16x16x32_bf16(af[mi], ones, acc[mi][4], 0, 0, 0);
            }
        }
    }
    float* base = partial + (size_t)(s * 16 + z) * 80 * 256;
#pragma unroll
    for (int mi = 0; mi < 4; mi++) {
        int f0r = w * 64 + mi * 16 + lq * 4;
#pragma unroll
        for (int ni = 0; ni < 5; ni++) {
            int col = ni * 16 + lr;
#pragma unroll
            for (int r = 0; r < 4; r++)
                base[(size_t)col * 256 + f0r + r] = acc[mi][ni][r];
        }
    }
}

// ---------------------------------------------------------------------------
__global__ __launch_bounds__(256) void ctx_reduce(const float* __restrict__ partial,
                                                  unsigned short* __restrict__ ctxT) {
    int idx = blockIdx.x * 256 + threadIdx.x;
    const int NC = 16 * 80 * 256;
    if (idx >= NC) return;
    float s = 0.f;
#pragma unroll
    for (int k = 0; k < 32; k++) s += partial[(size_t)k * NC + idx];
    ctxT[idx] = f2bf(s);
}

// ---------------------------------------------------------------------------
// Fused q' featuremap + (q'.ctx_ext) with D at col 64 -> bf16 attn out.
// ---------------------------------------------------------------------------
__global__ __launch_bounds__(256) void attn_fused_mfma(
    const unsigned short* __restrict__ qkvb,
    const unsigned short* __restrict__ projb,
    const unsigned short* __restrict__ ctxT,
    unsigned short* __restrict__ attnb)
{
    __shared__ __align__(16) unsigned short QB[16 * 512];
    __shared__ __align__(16) unsigned short PA[8 * 512];
    __shared__ __align__(16) unsigned short QPA[16 * 512];
    __shared__ __align__(16) unsigned short CB[10 * 512];
    const int t = threadIdx.x, w = t >> 6, l = t & 63;
    const int lr = l & 15, lq = l >> 4;
    const int m0 = blockIdx.x * 128, z = blockIdx.y;
    const int b = z >> 3, h = z & 7;

    for (int idx = w; idx < 16; idx += 4) {
        int mblk = idx >> 1, kt = idx & 1;
        glds16(qkvb + ((size_t)b * NSEQ + m0 + mblk * 16 + lr) * QKV_ + h * 64 + kt * 32 + lq * 8,
               &QB[idx * 512]);
    }
    float4v acc[2][5];
#pragma unroll
    for (int mi = 0; mi < 2; mi++)
#pragma unroll
        for (int ni = 0; ni < 5; ni++) acc[mi][ni] = (float4v){0.f, 0.f, 0.f, 0.f};

    for (int fs = 0; fs < 4; fs++) {
        int f0 = fs * 64;
        __syncthreads();
        for (int idx = w; idx < 8; idx += 4) {
            int fb = idx >> 1, kt = idx & 1;
            glds16(projb + (size_t)(f0 + fb * 16 + lr) * 64 + kt * 32 + lq * 8, &PA[idx * 512]);
        }
        for (int idx = w; idx < 10; idx += 4) {
            int dhb = idx >> 1, ft = idx & 1;
            glds16(ctxT + ((size_t)z * 80 + dhb * 16 + lr) * 256 + f0 + ft * 32 + lq * 8,
                   &CB[idx * 512]);
        }
        __syncthreads();

        float4v a2[4][2];
#pragma unroll
        for (int mi = 0; mi < 4; mi++)
#pragma unroll
            for (int ni = 0; ni < 2; ni++) a2[mi][ni] = (float4v){0.f, 0.f, 0.f, 0.f};
#pragma unroll
        for (int ks = 0; ks < 2; ks++) {
            short8 pa[4], qb[2];
#pragma unroll
            for (int mi = 0; mi < 4; mi++)
                pa[mi] = *(const short8*)&PA[((mi * 2 + ks) * 64 + l) * 8];
#pragma unroll
            for (int ni = 0; ni < 2; ni++)
                qb[ni] = *(const short8*)&QB[(((w * 2 + ni) * 2 + ks) * 64 + l) * 8];
#pragma unroll
            for (int mi = 0; mi < 4; mi++)
#pragma unroll
                for (int ni = 0; ni < 2; ni++)
                    a2[mi][ni] = __builtin_amdgcn_mfma_f32_16x16x32_bf16(pa[mi], qb[ni], a2[mi][ni], 0, 0, 0);
        }
#pragma unroll
        for (int mi = 0; mi < 4; mi++) {
            int fb2 = mi * 16 + lq * 4;
            int qoff = ((fb2 >> 3) & 3) * 256 + (fb2 & 7) * 2;
            int setf = fb2 >> 5;
#pragma unroll
            for (int ni = 0; ni < 2; ni++) {
                int m = w * 32 + ni * 16 + lr;
                float e0 = __expf(0.125f * a2[mi][ni][0]);
                float e1 = __expf(0.125f * a2[mi][ni][1]);
                float e2 = __expf(0.125f * a2[mi][ni][2]);
                float e3 = __expf(0.125f * a2[mi][ni][3]);
                uint2 p; p.x = pack2bf(e0, e1); p.y = pack2bf(e2, e3);
                *(uint2*)((char*)QPA + (size_t)(((m >> 4) * 2 + setf) * 1024 + qoff + (m & 15) * 16)) = p;
            }
        }
#pragma unroll
        for (int ks = 0; ks < 2; ks++) {
            short8 af[2], cb[5];
#pragma unroll
            for (int mi = 0; mi < 2; mi++)
                af[mi] = *(const short8*)&QPA[(((w * 2 + mi) * 2 + ks) * 64 + l) * 8];
#pragma unroll
            for (int ni = 0; ni < 5; ni++)
                cb[ni] = *(const short8*)&CB[((ni * 2 + ks) * 64 + l) * 8];
#pragma unroll
            for (int mi = 0; mi < 2; mi++)
#pragma unroll
                for (int ni = 0; ni < 5; ni++)
                    acc[mi][ni] = __builtin_amdgcn_mfma_f32_16x16x32_bf16(af[mi], cb[ni], acc[mi][ni], 0, 0, 0);
        }
    }
#pragma unroll
    for (int mi = 0; mi < 2; mi++) {
        int rowb = m0 + w * 32 + mi * 16 + lq * 4;
#pragma unroll
        for (int r = 0; r < 4; r++) {
            float dv = __shfl(acc[mi][4][r], (l & 48), 64);
            float rinv = 1.f / (dv + 1e-6f);
#pragma unroll
            for (int ni = 0; ni < 4; ni++)
                attnb[((size_t)b * NSEQ + rowb + r) * 512 + h * 64 + ni * 16 + lr] =
                    f2bf(acc[mi][ni][r] * rinv);
        }
    }
}

// ---------------------------------------------------------------------------
extern "C" void kernel_launch(void* const* d_in, const int* in_sizes, int n_in,
                              void* d_out, int out_size, void* d_ws, size_t ws_size,
                              hipStream_t stream) {
    const float* x    = (const float*)d_in[0];
    const float* Wqkv = (const float*)d_in[1];
    const float* Wout = (const float*)d_in[2];
    const float* bout = (const float*)d_in[3];
    const float* proj = (const float*)d_in[4];

    unsigned short* qkvb  = (unsigned short*)d_ws;                  // 25,165,824 u16
    unsigned short* vT    = qkvb + (size_t)M_ * QKV_;               // 8,388,608 u16
    float*          partial = (float*)(vT + (size_t)16 * 64 * NSEQ);// 10,485,760 f32
    unsigned short* ctxT  = (unsigned short*)(partial + (size_t)32 * 16 * 80 * 256); // 327,680 u16
    unsigned short* projb = ctxT + (size_t)16 * 80 * 256;           // 16,384 u16
    unsigned short* xb    = projb + 16384;                          // 8,388,608 u16
    unsigned short* attnb = xb;                                     // overlay (xb dead after gemm1)
    unsigned short* wqkvb = xb + (size_t)M_ * DIM_;                 // 786,432 u16
    unsigned short* woutb = wqkvb + (size_t)QKV_ * DIM_;            // 262,144 u16
    float* outp = (float*)d_out;                                    // total ws ~128.6 MB

    // 0) fp32 -> bf16 (single launch)
    cvt_all<<<dim3(4616), 256, 0, stream>>>(x, Wqkv, Wout, proj, xb, wqkvb, woutb, projb);
    // 1) qkv = x @ Wqkv^T  (bf16 out) — pipelined ping-pong, 128x128
    gemm_nt_pp<true><<<dim3(QKV_ / 128, M_ / 128), 256, 0, stream>>>(xb, wqkvb, nullptr, qkvb, M_, QKV_, DIM_);
    // 2) V transpose
    vtrans<<<dim3(64, 16), 256, 0, stream>>>(qkvb, vT);
    // 3) fused k' + context partials (MFMA)
    ctx_fused_mfma<<<dim3(32, 16), 256, 0, stream>>>(qkvb, projb, vT, partial);
    // 4) reduce -> ctxT bf16 (incl. ksum row)
    ctx_reduce<<<dim3(1280), 256, 0, stream>>>(partial, ctxT);
    // 5) fused q' + attention out (MFMA), bf16
    attn_fused_mfma<<<dim3(64, 16), 256, 0, stream>>>(qkvb, projb, ctxT, attnb);
    // 6) out = attn @ Wout^T + bout — pipelined ping-pong
    gemm_nt_pp<false><<<dim3(DIM_ / 128, M_ / 128), 256, 0, stream>>>(attnb, woutb, bout, outp, M_, DIM_, DIM_);
}